// Round 4
// baseline (3079.045 us; speedup 1.0000x reference)
//
#include <hip/hip_runtime.h>
#include <stdint.h>

// ---------------- problem constants ----------------
// B=4, DIM=192, H=W=64, N=4096, HEADS=8, HD=24, SR=4, PH=PW=16, PLEN=256, LL=9
// ALL inputs float32; OUTPUT float32 (R2/R3 failed only on storing bf16 output).

// ---------------- workspace layout (floats) ----------------
constexpr size_t OFF_T    = 0;          // (B,N,192) t (pre+post LN, in-place)
constexpr size_t OFF_KMAP = 3145728;    // (B,384,N) normalized k + v
constexpr size_t OFF_QN   = 9437184;    // (B,8,24,N)
constexpr size_t OFF_QS   = 12582912;   // (B,8,24,N)
constexpr size_t OFF_CTX  = 15728640;   // (B,8,24,N)
constexpr size_t OFF_POOL = 18874368;   // (B,256,192)
constexpr size_t OFF_KP   = 19070976;   // (B,8,256,24)
constexpr size_t OFF_VP   = 19267584;   // (B,8,256,24)
constexpr size_t OFF_CPB  = 19464192;   // (T,8)  T<=16384
constexpr size_t OFF_BIAS = 19595264;   // (8,256,4096)  -> end 27983872 floats (~112 MB)

// ---------------- 3x3 conv (pos-embed) + bias, writes t[b][n][o] ----------------
__global__ __launch_bounds__(256) void k_conv(
    const float* __restrict__ x, const float* __restrict__ wf,
    const float* __restrict__ bf, float* __restrict__ t) {
  __shared__ float xs[3 * 66 * 12];   // [r][wp(0..65)][ii(0..7)+pad]
  __shared__ float outs[64 * 33];
  const int tid = threadIdx.x;
  const int lane = tid & 63;
  const int wv = __builtin_amdgcn_readfirstlane(tid >> 6);
  const int og = blockIdx.x;   // 0..5   (32 outputs each)
  const int h  = blockIdx.y;   // 0..63
  const int b  = blockIdx.z;   // 0..3
  const int obase = og * 32 + wv * 8;

  float acc[8];
#pragma unroll
  for (int j = 0; j < 8; ++j) acc[j] = 0.f;

  for (int ic = 0; ic < 24; ++ic) {   // 8 input channels per chunk
    __syncthreads();
    for (int f = tid; f < 1584; f += 256) {
      int ii = f / 198;
      int rem = f - ii * 198;
      int r = rem / 66;
      int wp = rem - r * 66;
      int hh = h + r - 1;
      int ww = wp - 1;
      float v = 0.f;
      if (hh >= 0 && hh < 64 && ww >= 0 && ww < 64)
        v = x[((size_t)(b * 192 + ic * 8 + ii) << 12) + (hh << 6) + ww];
      xs[(r * 66 + wp) * 12 + ii] = v;
    }
    __syncthreads();
#pragma unroll
    for (int r = 0; r < 3; ++r) {
#pragma unroll
      for (int kw = 0; kw < 3; ++kw) {
        const float4* p4 = (const float4*)&xs[(r * 66 + lane + kw) * 12];
        float4 a0 = p4[0];
        float4 a1 = p4[1];
#pragma unroll
        for (int j = 0; j < 8; ++j) {
          const float* wp_ = wf + ((size_t)(obase + j) * 192 + ic * 8) * 9 + (r * 3 + kw);
          acc[j] += a0.x * wp_[0]  + a0.y * wp_[9]  + a0.z * wp_[18] + a0.w * wp_[27]
                  + a1.x * wp_[36] + a1.y * wp_[45] + a1.z * wp_[54] + a1.w * wp_[63];
        }
      }
    }
  }
#pragma unroll
  for (int j = 0; j < 8; ++j) outs[lane * 33 + wv * 8 + j] = acc[j] + bf[obase + j];
  __syncthreads();
  for (int f = tid; f < 2048; f += 256) {
    int ol = f & 31;
    int nl = f >> 5;
    t[((size_t)b * 4096 + h * 64 + nl) * 192 + og * 32 + ol] = outs[nl * 33 + ol];
  }
}

// ---------------- LN over 192 channels, in-place (wave per row) ----------------
__global__ __launch_bounds__(256) void k_ln_rows(float* __restrict__ data,
    const float* __restrict__ g, const float* __restrict__ be, int rows) {
  int lane = threadIdx.x & 63;
  int wv = threadIdx.x >> 6;
  int row = blockIdx.x * 4 + wv;
  if (row >= rows) return;
  float* p = data + (size_t)row * 192;
  float v0 = p[lane], v1 = p[lane + 64], v2 = p[lane + 128];
  float s = v0 + v1 + v2;
  float sq = v0 * v0 + v1 * v1 + v2 * v2;
#pragma unroll
  for (int m = 32; m >= 1; m >>= 1) {
    s += __shfl_xor(s, m, 64);
    sq += __shfl_xor(sq, m, 64);
  }
  float mean = s * (1.f / 192.f);
  float var = sq * (1.f / 192.f) - mean * mean;
  float rstd = rsqrtf(var + 1e-5f);
  p[lane]       = (v0 - mean) * rstd * g[lane]       + be[lane];
  p[lane + 64]  = (v1 - mean) * rstd * g[lane + 64]  + be[lane + 64];
  p[lane + 128] = (v2 - mean) * rstd * g[lane + 128] + be[lane + 128];
}

// ---------------- q = t@q_w.T + b -> l2norm -> scaled, out [b][h][d][n] ----------------
__global__ __launch_bounds__(256) void k_q(
    const float* __restrict__ t, const float* __restrict__ qw, const float* __restrict__ qb,
    const float* __restrict__ qe, const float* __restrict__ tmp, const float* __restrict__ ss,
    float* __restrict__ qno, float* __restrict__ qso) {
  __shared__ float ts[64 * 196];
  const int tid = threadIdx.x;
  const int lane = tid & 63;
  const int wv = __builtin_amdgcn_readfirstlane(tid >> 6);
  const int n0 = blockIdx.x * 64;
  const int b = blockIdx.y;
  for (int f = tid; f < 64 * 192; f += 256) {
    int c = f % 192;
    int nl = f / 192;
    ts[nl * 196 + c] = t[((size_t)b * 4096 + n0 + nl) * 192 + c];
  }
  __syncthreads();
  const int o0 = wv * 48;
  float acc[48];
#pragma unroll
  for (int j = 0; j < 48; ++j) acc[j] = 0.f;
  for (int k4 = 0; k4 < 48; ++k4) {
    float4 a = *(const float4*)&ts[lane * 196 + k4 * 4];
#pragma unroll
    for (int j = 0; j < 48; ++j) {
      const float* wr = qw + (size_t)(o0 + j) * 192 + k4 * 4;
      acc[j] += a.x * wr[0] + a.y * wr[1] + a.z * wr[2] + a.w * wr[3];
    }
  }
  const int n = n0 + lane;
  float ssv = ss[n];
#pragma unroll
  for (int hl = 0; hl < 2; ++hl) {
    int hh = 2 * wv + hl;
    float sumsq = 0.f;
#pragma unroll
    for (int d = 0; d < 24; ++d) {
      float v = acc[hl * 24 + d] + qb[o0 + hl * 24 + d];
      sumsq += v * v;
    }
    float rn = 1.f / fmaxf(sqrtf(sumsq), 1e-12f);
    float sp = log1pf(__expf(tmp[hh]));
#pragma unroll
    for (int d = 0; d < 24; ++d) {
      float qv = (acc[hl * 24 + d] + qb[o0 + hl * 24 + d]) * rn;
      size_t o = ((size_t)(b * 8 + hh) * 24 + d) * 4096 + n;
      qno[o] = qv;
      qso[o] = (qv + qe[hh * 24 + d]) * sp * ssv;
    }
  }
}

// ---------------- kv = t@kv_w.T + b -> kmap[b][c][n] (k l2-normed, v raw) ----------------
__global__ __launch_bounds__(256) void k_kv(
    const float* __restrict__ t, const float* __restrict__ kw_, const float* __restrict__ kb_,
    float* __restrict__ kmap) {
  __shared__ float ts[64 * 196];
  const int tid = threadIdx.x;
  const int lane = tid & 63;
  const int wv = __builtin_amdgcn_readfirstlane(tid >> 6);
  const int n0 = blockIdx.x * 64;
  const int b = blockIdx.y;
  for (int f = tid; f < 64 * 192; f += 256) {
    int c = f % 192;
    int nl = f / 192;
    ts[nl * 196 + c] = t[((size_t)b * 4096 + n0 + nl) * 192 + c];
  }
  __syncthreads();
  const int n = n0 + lane;
  for (int s = 0; s < 2; ++s) {
    const int o0 = s * 192 + wv * 48;
    float acc[48];
#pragma unroll
    for (int j = 0; j < 48; ++j) acc[j] = 0.f;
    for (int k4 = 0; k4 < 48; ++k4) {
      float4 a = *(const float4*)&ts[lane * 196 + k4 * 4];
#pragma unroll
      for (int j = 0; j < 48; ++j) {
        const float* wr = kw_ + (size_t)(o0 + j) * 192 + k4 * 4;
        acc[j] += a.x * wr[0] + a.y * wr[1] + a.z * wr[2] + a.w * wr[3];
      }
    }
    if (s == 0) {
#pragma unroll
      for (int hl = 0; hl < 2; ++hl) {
        float sumsq = 0.f;
#pragma unroll
        for (int d = 0; d < 24; ++d) {
          float v = acc[hl * 24 + d] + kb_[o0 + hl * 24 + d];
          sumsq += v * v;
        }
        float rn = 1.f / fmaxf(sqrtf(sumsq), 1e-12f);
#pragma unroll
        for (int d = 0; d < 24; ++d) {
          float v = (acc[hl * 24 + d] + kb_[o0 + hl * 24 + d]) * rn;
          kmap[((size_t)b * 384 + wv * 48 + hl * 24 + d) * 4096 + n] = v;
        }
      }
    } else {
#pragma unroll
      for (int j = 0; j < 48; ++j)
        kmap[((size_t)b * 384 + 192 + wv * 48 + j) * 4096 + n] = acc[j] + kb_[o0 + j];
    }
  }
}

// ---------------- sr GEMM + exact gelu + 4x4 mean-pool ----------------
__device__ __forceinline__ float gelu_exact(float v) {
  float u = v * 0.70710678118654752f;
  float a = fabsf(u);
  float tt = 1.f / (1.f + 0.3275911f * a);
  float poly = ((((1.061405429f * tt - 1.453152027f) * tt + 1.421413741f) * tt
                 - 0.284496736f) * tt + 0.254829592f) * tt;
  float erfa = 1.f - poly * __expf(-a * a);
  float erfv = (u < 0.f) ? -erfa : erfa;
  return 0.5f * v * (1.f + erfv);
}

__global__ __launch_bounds__(256) void k_srpool(
    const float* __restrict__ t, const float* __restrict__ sw, const float* __restrict__ sb,
    float* __restrict__ pooled) {
  __shared__ float ts[64 * 196];
  const int tid = threadIdx.x;
  const int lane = tid & 63;
  const int wv = __builtin_amdgcn_readfirstlane(tid >> 6);
  const int wx = blockIdx.x;  // 0..3 (16 w each)
  const int ph = blockIdx.y;  // 0..15 (4 h each)
  const int b = blockIdx.z;
  for (int f = tid; f < 64 * 192; f += 256) {
    int c = f % 192;
    int pl = f / 192;
    int hh2 = pl >> 4;
    int ww2 = pl & 15;
    int row = (ph * 4 + hh2) * 64 + wx * 16 + ww2;
    ts[pl * 196 + c] = t[((size_t)b * 4096 + row) * 192 + c];
  }
  __syncthreads();
  const int o0 = wv * 48;
  float acc[48];
#pragma unroll
  for (int j = 0; j < 48; ++j) acc[j] = 0.f;
  for (int k4 = 0; k4 < 48; ++k4) {
    float4 a = *(const float4*)&ts[lane * 196 + k4 * 4];
#pragma unroll
    for (int j = 0; j < 48; ++j) {
      const float* wr = sw + (size_t)(o0 + j) * 192 + k4 * 4;
      acc[j] += a.x * wr[0] + a.y * wr[1] + a.z * wr[2] + a.w * wr[3];
    }
  }
#pragma unroll
  for (int j = 0; j < 48; ++j) {
    float gv = gelu_exact(acc[j] + sb[o0 + j]);
    gv += __shfl_xor(gv, 1, 64);
    gv += __shfl_xor(gv, 2, 64);
    gv += __shfl_xor(gv, 16, 64);
    gv += __shfl_xor(gv, 32, 64);
    if ((lane & 51) == 0) {   // ww%4==0 && hh==0
      int cell = (lane >> 2) & 3;
      int p = ph * 16 + wx * 4 + cell;
      pooled[((size_t)b * 256 + p) * 192 + o0 + j] = gv * (1.f / 16.f);
    }
  }
}

// ---------------- pooled kv: kp (l2-normed) / vp, [b][h][m][d] ----------------
__global__ __launch_bounds__(256) void k_kvp(
    const float* __restrict__ pooled, const float* __restrict__ kw_, const float* __restrict__ kb_,
    float* __restrict__ kp, float* __restrict__ vp) {
  __shared__ float ts[64 * 196];
  const int tid = threadIdx.x;
  const int lane = tid & 63;
  const int wv = __builtin_amdgcn_readfirstlane(tid >> 6);
  const int r0 = blockIdx.x * 64;
  for (int f = tid; f < 64 * 192; f += 256) {
    int c = f % 192;
    int nl = f / 192;
    ts[nl * 196 + c] = pooled[((size_t)(r0 + nl)) * 192 + c];
  }
  __syncthreads();
  const int row = r0 + lane;
  const int b = row >> 8;
  const int m = row & 255;
  for (int s = 0; s < 2; ++s) {
    const int o0 = s * 192 + wv * 48;
    float acc[48];
#pragma unroll
    for (int j = 0; j < 48; ++j) acc[j] = 0.f;
    for (int k4 = 0; k4 < 48; ++k4) {
      float4 a = *(const float4*)&ts[lane * 196 + k4 * 4];
#pragma unroll
      for (int j = 0; j < 48; ++j) {
        const float* wr = kw_ + (size_t)(o0 + j) * 192 + k4 * 4;
        acc[j] += a.x * wr[0] + a.y * wr[1] + a.z * wr[2] + a.w * wr[3];
      }
    }
#pragma unroll
    for (int hl = 0; hl < 2; ++hl) {
      int hh = 2 * wv + hl;
      if (s == 0) {
        float sumsq = 0.f;
#pragma unroll
        for (int d = 0; d < 24; ++d) {
          float v = acc[hl * 24 + d] + kb_[o0 + hl * 24 + d];
          sumsq += v * v;
        }
        float rn = 1.f / fmaxf(sqrtf(sumsq), 1e-12f);
#pragma unroll
        for (int d = 0; d < 24; ++d) {
          float v = (acc[hl * 24 + d] + kb_[o0 + hl * 24 + d]) * rn;
          kp[(((size_t)(b * 8 + hh)) * 256 + m) * 24 + d] = v;
        }
      } else {
#pragma unroll
        for (int d = 0; d < 24; ++d)
          vp[(((size_t)(b * 8 + hh)) * 256 + m) * 24 + d] =
              acc[hl * 24 + d] + kb_[o0 + hl * 24 + d];
      }
    }
  }
}

// ---------------- cpb MLP: (T,2) -> (T,8) ----------------
__global__ __launch_bounds__(256) void k_cpb(
    const float* __restrict__ coords, const float* __restrict__ c1w,
    const float* __restrict__ c1b, const float* __restrict__ c2w,
    const float* __restrict__ c2b, float* __restrict__ cpb, int T) {
  int i = blockIdx.x * 256 + threadIdx.x;
  if (i >= T) return;
  float x0 = coords[2 * i], y0 = coords[2 * i + 1];
  float a[8];
#pragma unroll
  for (int h = 0; h < 8; ++h) a[h] = c2b[h];
  for (int j = 0; j < 512; ++j) {
    float hv = fmaxf(c1w[2 * j] * x0 + c1w[2 * j + 1] * y0 + c1b[j], 0.f);
#pragma unroll
    for (int h = 0; h < 8; ++h) a[h] += hv * c2w[h * 512 + j];
  }
#pragma unroll
  for (int h = 0; h < 8; ++h) cpb[(size_t)i * 8 + h] = a[h];
}

// ---------------- pool bias gather: bt[h][m][n] = cpb[rel_idx[n*256+m]][h] ----------------
__global__ __launch_bounds__(256) void k_bias(
    const int* __restrict__ rel, const float* __restrict__ cpb, float* __restrict__ bt) {
  int n = blockIdx.x * 256 + threadIdx.x;
  int m = blockIdx.y;
  int idx = rel[(size_t)n * 256 + m];
  const float4* c4 = (const float4*)(cpb + (size_t)idx * 8);
  float4 A = c4[0], Bv = c4[1];
  float vals[8] = {A.x, A.y, A.z, A.w, Bv.x, Bv.y, Bv.z, Bv.w};
#pragma unroll
  for (int h = 0; h < 8; ++h)
    bt[((size_t)(h * 256 + m)) * 4096 + n] = vals[h];
}

// ---------------- fused attention (local 9 + pool 256, shared softmax) ----------------
// Uniform logit shift of -15 before exp: softmax-invariant, bounds exp() away from inf.
__global__ __launch_bounds__(256) void k_attn(
    const float* __restrict__ qs_g, const float* __restrict__ qn_g,
    const float* __restrict__ kmap, const float* __restrict__ kp, const float* __restrict__ vp,
    const float* __restrict__ bt, const float* __restrict__ rpb,
    const float* __restrict__ lt, const float* __restrict__ lb,
    float* __restrict__ ctx) {
  const int tid = threadIdx.x;
  const int lane = tid & 63;
  const int wv = __builtin_amdgcn_readfirstlane(tid >> 6);
  const int h = blockIdx.y;
  const int b = blockIdx.z;
  const int n = blockIdx.x * 256 + wv * 64 + lane;
  const int hpix = __builtin_amdgcn_readfirstlane(n >> 6);
  const int wpix = n & 63;
  const float SHIFT = 15.f;

  float qsv[24], qnv[24];
  const float* qsb = qs_g + ((size_t)(b * 8 + h) * 24) * 4096 + n;
  const float* qnb = qn_g + ((size_t)(b * 8 + h) * 24) * 4096 + n;
#pragma unroll
  for (int d = 0; d < 24; ++d) {
    qsv[d] = qsb[(size_t)d * 4096];
    qnv[d] = qnb[(size_t)d * 4096];
  }

  const float* ltp = lt + h * 216;
  const float* lbp = lb + h * 9;
  const float* rpp = rpb + h * 9;
  float wl[9];
#pragma unroll
  for (int l = 0; l < 9; ++l) {
    float a0 = 0, a1 = 0, a2 = 0;
#pragma unroll
    for (int d = 0; d < 24; d += 3) {
      a0 += qnv[d] * ltp[d * 9 + l];
      a1 += qnv[d + 1] * ltp[(d + 1) * 9 + l];
      a2 += qnv[d + 2] * ltp[(d + 2) * 9 + l];
    }
    wl[l] = a0 + a1 + a2 + lbp[l];
  }

  float ctxA[24], ctxB[24], ctxP[24];
#pragma unroll
  for (int d = 0; d < 24; ++d) { ctxA[d] = 0.f; ctxB[d] = 0.f; ctxP[d] = 0.f; }
  float S = 0.f;

  const float* kbase = kmap + ((size_t)b * 384 + h * 24) * 4096;
#pragma unroll
  for (int l = 0; l < 9; ++l) {
    const int dh = l / 3 - 1, dw = l % 3 - 1;
    const int hp = hpix + dh;
    if (hp < 0 || hp >= 64) continue;   // wave-uniform
    const int wp2 = wpix + dw;
    const bool okw = (wp2 >= 0) && (wp2 < 64);
    const int nn = (hp << 6) + wp2;
    const float* kb = kbase + nn;
    const float* vb = kb + (size_t)192 * 4096;
    float d0 = 0, d1 = 0, d2 = 0, d3 = 0;
#pragma unroll
    for (int d = 0; d < 24; d += 4) {
      d0 += qsv[d] * kb[(size_t)d * 4096];
      d1 += qsv[d + 1] * kb[(size_t)(d + 1) * 4096];
      d2 += qsv[d + 2] * kb[(size_t)(d + 2) * 4096];
      d3 += qsv[d + 3] * kb[(size_t)(d + 3) * 4096];
    }
    float p = okw ? __expf((d0 + d1) + (d2 + d3) + rpp[l] - SHIFT) : 0.f;
    S += p;
    float wll = wl[l];
#pragma unroll
    for (int d = 0; d < 24; ++d) {
      float vv = okw ? vb[(size_t)d * 4096] : 0.f;
      ctxA[d] += wll * vv;
      ctxB[d] += p * vv;
    }
  }

  const float* kpb = kp + (size_t)(b * 8 + h) * 256 * 24;
  const float* vpb = vp + (size_t)(b * 8 + h) * 256 * 24;
  const float* bb = bt + (size_t)(h * 256) * 4096 + n;
#pragma unroll 2
  for (int m = 0; m < 256; ++m) {
    const float* kr = kpb + m * 24;
    const float* vr = vpb + m * 24;
    float d0 = 0, d1 = 0, d2 = 0, d3 = 0;
#pragma unroll
    for (int d = 0; d < 24; d += 4) {
      d0 += qsv[d] * kr[d];
      d1 += qsv[d + 1] * kr[d + 1];
      d2 += qsv[d + 2] * kr[d + 2];
      d3 += qsv[d + 3] * kr[d + 3];
    }
    float p = __expf((d0 + d1) + (d2 + d3) + bb[(size_t)m * 4096] - SHIFT);
    S += p;
#pragma unroll
    for (int d = 0; d < 24; ++d) ctxP[d] += p * vr[d];
  }

  const float inv = 1.f / S;
  float* cb = ctx + ((size_t)(b * 8 + h) * 24) * 4096 + n;
#pragma unroll
  for (int d = 0; d < 24; ++d)
    cb[(size_t)d * 4096] = ctxA[d] + (ctxB[d] + ctxP[d]) * inv;
}

// ---------------- proj + output LN + f32 store, out[b][o][n] ----------------
__global__ __launch_bounds__(256) void k_proj(
    const float* __restrict__ ctx, const float* __restrict__ pw, const float* __restrict__ pb,
    const float* __restrict__ g, const float* __restrict__ be,
    float* __restrict__ out) {
  __shared__ float ts[64 * 196];
  __shared__ float red[2][4][64];
  const int tid = threadIdx.x;
  const int lane = tid & 63;
  const int wv = __builtin_amdgcn_readfirstlane(tid >> 6);
  const int n0 = blockIdx.x * 64;
  const int b = blockIdx.y;
  for (int f = tid; f < 64 * 192; f += 256) {
    int nl = f & 63;
    int c = f >> 6;
    ts[nl * 196 + c] = ctx[((size_t)b * 192 + c) * 4096 + n0 + nl];
  }
  __syncthreads();
  const int o0 = wv * 48;
  float acc[48];
#pragma unroll
  for (int j = 0; j < 48; ++j) acc[j] = 0.f;
  for (int k4 = 0; k4 < 48; ++k4) {
    float4 a = *(const float4*)&ts[lane * 196 + k4 * 4];
#pragma unroll
    for (int j = 0; j < 48; ++j) {
      const float* wr = pw + (size_t)(o0 + j) * 192 + k4 * 4;
      acc[j] += a.x * wr[0] + a.y * wr[1] + a.z * wr[2] + a.w * wr[3];
    }
  }
  float s = 0, sq = 0;
#pragma unroll
  for (int j = 0; j < 48; ++j) {
    acc[j] += pb[o0 + j];
    s += acc[j];
    sq += acc[j] * acc[j];
  }
  red[0][wv][lane] = s;
  red[1][wv][lane] = sq;
  __syncthreads();
  float st = red[0][0][lane] + red[0][1][lane] + red[0][2][lane] + red[0][3][lane];
  float sqt = red[1][0][lane] + red[1][1][lane] + red[1][2][lane] + red[1][3][lane];
  float mean = st * (1.f / 192.f);
  float var = sqt * (1.f / 192.f) - mean * mean;
  float rstd = rsqrtf(var + 1e-5f);
#pragma unroll
  for (int j = 0; j < 48; ++j) {
    int o = o0 + j;
    float v = (acc[j] - mean) * rstd * g[o] + be[o];
    out[((size_t)b * 192 + o) * 4096 + n0 + lane] = v;   // f32 store (the R2/R3 fix)
  }
}

// ---------------- host launcher ----------------
extern "C" void kernel_launch(void* const* d_in, const int* in_sizes, int n_in,
                              void* d_out, int out_size, void* d_ws, size_t ws_size,
                              hipStream_t stream) {
  float* w = (float*)d_ws;

  const float* x      = (const float*)d_in[0];
  const float* pe_w   = (const float*)d_in[1];
  const float* pe_b   = (const float*)d_in[2];
  const float* peln_g = (const float*)d_in[3];
  const float* peln_b = (const float*)d_in[4];
  const float* q_w    = (const float*)d_in[5];
  const float* q_b    = (const float*)d_in[6];
  const float* kv_w   = (const float*)d_in[7];
  const float* kv_b   = (const float*)d_in[8];
  const float* sr_w   = (const float*)d_in[9];
  const float* sr_b   = (const float*)d_in[10];
  const float* norm_g = (const float*)d_in[11];
  const float* norm_b = (const float*)d_in[12];
  const float* cpb1w  = (const float*)d_in[13];
  const float* cpb1b  = (const float*)d_in[14];
  const float* cpb2w  = (const float*)d_in[15];
  const float* cpb2b  = (const float*)d_in[16];
  const float* rpb    = (const float*)d_in[17];
  const float* lt     = (const float*)d_in[18];
  const float* lb     = (const float*)d_in[19];
  const float* qe     = (const float*)d_in[20];
  const float* temp   = (const float*)d_in[21];
  const float* proj_w = (const float*)d_in[22];
  const float* proj_b = (const float*)d_in[23];
  const float* oln_g  = (const float*)d_in[24];
  const float* oln_b  = (const float*)d_in[25];
  const int*   rel    = (const int*)d_in[26];
  const float* coords = (const float*)d_in[27];
  const float* ss     = (const float*)d_in[28];
  // d_in[29] pad_mask (bool) unused — masks recomputed analytically.

  dim3 blk(256);
  k_conv<<<dim3(6, 64, 4), blk, 0, stream>>>(x, pe_w, pe_b, w + OFF_T);
  k_ln_rows<<<dim3(4096), blk, 0, stream>>>(w + OFF_T, peln_g, peln_b, 16384);
  k_q<<<dim3(64, 4), blk, 0, stream>>>(w + OFF_T, q_w, q_b, qe, temp, ss,
      w + OFF_QN, w + OFF_QS);
  k_kv<<<dim3(64, 4), blk, 0, stream>>>(w + OFF_T, kv_w, kv_b, w + OFF_KMAP);
  k_srpool<<<dim3(4, 16, 4), blk, 0, stream>>>(w + OFF_T, sr_w, sr_b, w + OFF_POOL);
  k_ln_rows<<<dim3(256), blk, 0, stream>>>(w + OFF_POOL, norm_g, norm_b, 1024);
  k_kvp<<<dim3(16), blk, 0, stream>>>(w + OFF_POOL, kv_w, kv_b, w + OFF_KP, w + OFF_VP);
  int T = in_sizes[27] / 2;
  k_cpb<<<dim3((T + 255) / 256), blk, 0, stream>>>(coords, cpb1w, cpb1b, cpb2w, cpb2b,
      w + OFF_CPB, T);
  k_bias<<<dim3(16, 256), blk, 0, stream>>>(rel, w + OFF_CPB, w + OFF_BIAS);
  k_attn<<<dim3(16, 8, 4), blk, 0, stream>>>(w + OFF_QS, w + OFF_QN, w + OFF_KMAP,
      w + OFF_KP, w + OFF_VP, w + OFF_BIAS, rpb, lt, lb, w + OFF_CTX);
  k_proj<<<dim3(64, 4), blk, 0, stream>>>(w + OFF_CTX, proj_w, proj_b, oln_g, oln_b,
      (float*)d_out);
}

// Round 6
// 1325.529 us; speedup vs baseline: 2.3229x; 2.3229x over previous
//
#include <hip/hip_runtime.h>
#include <stdint.h>

// B=4, DIM=192, H=W=64, N=4096, HEADS=8, HD=24, SR=4, PLEN=256, LL=9
// All inputs f32, output f32.

// ---------------- workspace layout (floats) ----------------
constexpr size_t OFF_T    = 0;          // (B,N,192)
constexpr size_t OFF_KMAP = 3145728;    // (B,384,N)
constexpr size_t OFF_QN   = 9437184;    // (B,8,24,N)
constexpr size_t OFF_QS   = 12582912;   // (B,8,24,N)
constexpr size_t OFF_CTX  = 15728640;   // (B,8,24,N)  (early: scratch for W transposes)
constexpr size_t OFF_POOL = 18874368;   // (B,256,192)
constexpr size_t OFF_KP   = 19070976;   // (B,8,256,24)
constexpr size_t OFF_VP   = 19267584;   // (B,8,256,24)
constexpr size_t OFF_CPB  = 19464192;   // (T,8)
constexpr size_t OFF_BIAS = 19595264;   // (8,256,4096) -> end 27983872 floats (~112 MB)
// transposed weights live in regions that are dead at their time of use:
constexpr size_t OFF_WTC  = OFF_CTX;              // conv wt [1728][192]
constexpr size_t OFF_QT   = OFF_CTX + 331776;     // [192][192]
constexpr size_t OFF_KVT  = OFF_CTX + 368640;     // [192][384]
constexpr size_t OFF_SRT  = OFF_CTX + 442368;     // [192][192]
constexpr size_t OFF_PJT  = OFF_KMAP;             // [192][192], created AFTER attn

// ---------------- weight transposes ----------------
__global__ __launch_bounds__(256) void k_wt_conv(const float* __restrict__ pw,
                                                 float* __restrict__ wt) {
  int i = blockIdx.x * 256 + threadIdx.x;
  if (i >= 331776) return;
  int oc = i % 192, k = i / 192;
  wt[i] = pw[(size_t)oc * 1728 + k];
}
__global__ __launch_bounds__(256) void k_wt_gen(const float* __restrict__ src,
                                                float* __restrict__ dst, int O, int K) {
  int i = blockIdx.x * 256 + threadIdx.x;
  if (i >= O * K) return;
  int o = i % O, k = i / O;
  dst[i] = src[(size_t)o * K + k];
}

// ---------------- 3x3 conv as implicit GEMM; grid (64 h, 4 b); t[b][n][oc] ----------------
__global__ __launch_bounds__(256) void k_conv(
    const float* __restrict__ x, const float* __restrict__ wtc,
    const float* __restrict__ bf, float* __restrict__ t) {
  __shared__ __align__(16) float wl[72 * 192];   // [k=ii*9+tap][oc]
  __shared__ float xl[8 * 198];                  // [ii][r][wp 0..65]
  const int tid = threadIdx.x;
  const int lane = tid & 63;
  const int wv = __builtin_amdgcn_readfirstlane(tid >> 6);
  const int h = blockIdx.x;
  const int b = blockIdx.y;
  const int o0 = wv * 48;

  float acc[48];
#pragma unroll
  for (int j = 0; j < 48; ++j) acc[j] = 0.f;

  for (int ic0 = 0; ic0 < 24; ++ic0) {
    __syncthreads();
    for (int f = tid; f < 1584; f += 256) {
      int ii = f / 198;
      int rem = f - ii * 198;
      int r = rem / 66;
      int wp = rem - r * 66;
      int hh = h + r - 1, ww = wp - 1;
      float v = 0.f;
      if (hh >= 0 && hh < 64 && ww >= 0 && ww < 64)
        v = x[((size_t)(b * 192 + ic0 * 8 + ii) << 12) + (hh << 6) + ww];
      xl[ii * 198 + r * 66 + wp] = v;
    }
    const float4* wsrc = (const float4*)(wtc + (size_t)ic0 * 72 * 192);
    float4* wld = (float4*)wl;
    for (int f = tid; f < 3456; f += 256) wld[f] = wsrc[f];
    __syncthreads();
#pragma unroll 1
    for (int ii = 0; ii < 8; ++ii) {
#pragma unroll
      for (int r = 0; r < 3; ++r) {
        const float* xrow = &xl[ii * 198 + r * 66 + lane];
        float xv0 = xrow[0], xv1 = xrow[1], xv2 = xrow[2];
#pragma unroll
        for (int kw = 0; kw < 3; ++kw) {
          float xv = (kw == 0) ? xv0 : ((kw == 1) ? xv1 : xv2);
          const float4* wrow = (const float4*)&wl[(ii * 9 + r * 3 + kw) * 192 + o0];
#pragma unroll
          for (int j4 = 0; j4 < 12; ++j4) {
            float4 w4 = wrow[j4];
            acc[j4 * 4 + 0] += xv * w4.x;
            acc[j4 * 4 + 1] += xv * w4.y;
            acc[j4 * 4 + 2] += xv * w4.z;
            acc[j4 * 4 + 3] += xv * w4.w;
          }
        }
      }
    }
  }
  float* outp = t + ((size_t)b * 4096 + h * 64 + lane) * 192 + o0;
#pragma unroll
  for (int j4 = 0; j4 < 12; ++j4) {
    float4 v;
    v.x = acc[j4 * 4 + 0] + bf[o0 + j4 * 4 + 0];
    v.y = acc[j4 * 4 + 1] + bf[o0 + j4 * 4 + 1];
    v.z = acc[j4 * 4 + 2] + bf[o0 + j4 * 4 + 2];
    v.w = acc[j4 * 4 + 3] + bf[o0 + j4 * 4 + 3];
    ((float4*)outp)[j4] = v;
  }
}

// ---------------- LN over 192 channels, in-place (wave per row) ----------------
__global__ __launch_bounds__(256) void k_ln_rows(float* __restrict__ data,
    const float* __restrict__ g, const float* __restrict__ be, int rows) {
  int lane = threadIdx.x & 63;
  int wv = threadIdx.x >> 6;
  int row = blockIdx.x * 4 + wv;
  if (row >= rows) return;
  float* p = data + (size_t)row * 192;
  float v0 = p[lane], v1 = p[lane + 64], v2 = p[lane + 128];
  float s = v0 + v1 + v2;
  float sq = v0 * v0 + v1 * v1 + v2 * v2;
#pragma unroll
  for (int m = 32; m >= 1; m >>= 1) {
    s += __shfl_xor(s, m, 64);
    sq += __shfl_xor(sq, m, 64);
  }
  float mean = s * (1.f / 192.f);
  float var = sq * (1.f / 192.f) - mean * mean;
  float rstd = rsqrtf(var + 1e-5f);
  p[lane]       = (v0 - mean) * rstd * g[lane]       + be[lane];
  p[lane + 64]  = (v1 - mean) * rstd * g[lane + 64]  + be[lane + 64];
  p[lane + 128] = (v2 - mean) * rstd * g[lane + 128] + be[lane + 128];
}

// ======== shared GEMM tile core: xs[kk][pixel(66)], wl[kk][oc(192)], acc 48/lane ========
template <typename StageX, typename StageW>
__device__ __forceinline__ void gemm_tile_loop(
    float* __restrict__ wl, float* __restrict__ xs, int tid, int lane, int o0,
    float (&acc)[48], StageX stage_x, StageW stage_w) {
  for (int kt = 0; kt < 6; ++kt) {
    const int k0 = kt * 32;
    __syncthreads();
    stage_x(k0);
    for (int f = tid; f < 6144; f += 256) {
      int kk = f / 192, oc = f - kk * 192;
      wl[f] = stage_w(k0 + kk, oc);
    }
    __syncthreads();
#pragma unroll 4
    for (int kk = 0; kk < 32; ++kk) {
      float xv = xs[kk * 66 + lane];
      const float4* wrow = (const float4*)&wl[kk * 192 + o0];
#pragma unroll
      for (int j4 = 0; j4 < 12; ++j4) {
        float4 w4 = wrow[j4];
        acc[j4 * 4 + 0] += xv * w4.x;
        acc[j4 * 4 + 1] += xv * w4.y;
        acc[j4 * 4 + 2] += xv * w4.z;
        acc[j4 * 4 + 3] += xv * w4.w;
      }
    }
  }
}

// ---------------- q GEMM -> l2norm -> scaled; [b][h][d][n] ----------------
__global__ __launch_bounds__(256) void k_q(
    const float* __restrict__ t, const float* __restrict__ qt, const float* __restrict__ qb,
    const float* __restrict__ qe, const float* __restrict__ tmp, const float* __restrict__ ss,
    float* __restrict__ qno, float* __restrict__ qso) {
  __shared__ __align__(16) float wl[32 * 192];
  __shared__ float xs[32 * 66];
  const int tid = threadIdx.x;
  const int lane = tid & 63;
  const int wv = __builtin_amdgcn_readfirstlane(tid >> 6);
  const int n0 = blockIdx.x * 64;
  const int b = blockIdx.y;
  const int o0 = wv * 48;
  float acc[48];
#pragma unroll
  for (int j = 0; j < 48; ++j) acc[j] = 0.f;

  gemm_tile_loop(wl, xs, tid, lane, o0, acc,
    [&](int k0) {
      for (int f = tid; f < 2048; f += 256) {
        int nl = f >> 5, kk = f & 31;
        xs[kk * 66 + nl] = t[((size_t)b * 4096 + n0 + nl) * 192 + k0 + kk];
      }
    },
    [&](int k, int oc) { return qt[(size_t)k * 192 + oc]; });

  const int n = n0 + lane;
  float ssv = ss[n];
#pragma unroll
  for (int hl = 0; hl < 2; ++hl) {
    int hh = 2 * wv + hl;
    float sumsq = 0.f;
#pragma unroll
    for (int d = 0; d < 24; ++d) {
      float v = acc[hl * 24 + d] + qb[o0 + hl * 24 + d];
      sumsq += v * v;
    }
    float rn = 1.f / fmaxf(sqrtf(sumsq), 1e-12f);
    float sp = log1pf(__expf(tmp[hh]));
#pragma unroll
    for (int d = 0; d < 24; ++d) {
      float qv = (acc[hl * 24 + d] + qb[o0 + hl * 24 + d]) * rn;
      size_t o = ((size_t)(b * 8 + hh) * 24 + d) * 4096 + n;
      qno[o] = qv;
      qso[o] = (qv + qe[hh * 24 + d]) * sp * ssv;
    }
  }
}

// ---------------- kv GEMM -> kmap[b][c][n] (k l2-normed, v raw) ----------------
__global__ __launch_bounds__(256) void k_kv(
    const float* __restrict__ t, const float* __restrict__ kvt, const float* __restrict__ kb_,
    float* __restrict__ kmap) {
  __shared__ __align__(16) float wl[32 * 192];
  __shared__ float xs[32 * 66];
  const int tid = threadIdx.x;
  const int lane = tid & 63;
  const int wv = __builtin_amdgcn_readfirstlane(tid >> 6);
  const int n0 = blockIdx.x * 64;
  const int b = blockIdx.y;
  const int o0 = wv * 48;
  const int n = n0 + lane;
  for (int s = 0; s < 2; ++s) {
    float acc[48];
#pragma unroll
    for (int j = 0; j < 48; ++j) acc[j] = 0.f;

    gemm_tile_loop(wl, xs, tid, lane, o0, acc,
      [&](int k0) {
        for (int f = tid; f < 2048; f += 256) {
          int nl = f >> 5, kk = f & 31;
          xs[kk * 66 + nl] = t[((size_t)b * 4096 + n0 + nl) * 192 + k0 + kk];
        }
      },
      [&](int k, int oc) { return kvt[(size_t)k * 384 + s * 192 + oc]; });

    const int ob = s * 192 + o0;
    if (s == 0) {
#pragma unroll
      for (int hl = 0; hl < 2; ++hl) {
        float sumsq = 0.f;
#pragma unroll
        for (int d = 0; d < 24; ++d) {
          float v = acc[hl * 24 + d] + kb_[ob + hl * 24 + d];
          sumsq += v * v;
        }
        float rn = 1.f / fmaxf(sqrtf(sumsq), 1e-12f);
#pragma unroll
        for (int d = 0; d < 24; ++d) {
          float v = (acc[hl * 24 + d] + kb_[ob + hl * 24 + d]) * rn;
          kmap[((size_t)b * 384 + o0 + hl * 24 + d) * 4096 + n] = v;
        }
      }
    } else {
#pragma unroll
      for (int j = 0; j < 48; ++j)
        kmap[((size_t)b * 384 + 192 + o0 + j) * 4096 + n] = acc[j] + kb_[ob + j];
    }
    __syncthreads();
  }
}

// ---------------- sr GEMM + exact gelu + 4x4 mean-pool ----------------
__device__ __forceinline__ float gelu_exact(float v) {
  float u = v * 0.70710678118654752f;
  float a = fabsf(u);
  float tt = 1.f / (1.f + 0.3275911f * a);
  float poly = ((((1.061405429f * tt - 1.453152027f) * tt + 1.421413741f) * tt
                 - 0.284496736f) * tt + 0.254829592f) * tt;
  float erfa = 1.f - poly * __expf(-a * a);
  float erfv = (u < 0.f) ? -erfa : erfa;
  return 0.5f * v * (1.f + erfv);
}

__global__ __launch_bounds__(256) void k_srpool(
    const float* __restrict__ t, const float* __restrict__ srt, const float* __restrict__ sb,
    float* __restrict__ pooled) {
  __shared__ __align__(16) float wl[32 * 192];
  __shared__ float xs[32 * 66];
  const int tid = threadIdx.x;
  const int lane = tid & 63;
  const int wv = __builtin_amdgcn_readfirstlane(tid >> 6);
  const int wx = blockIdx.x;  // 0..3
  const int ph = blockIdx.y;  // 0..15
  const int b = blockIdx.z;
  const int o0 = wv * 48;
  float acc[48];
#pragma unroll
  for (int j = 0; j < 48; ++j) acc[j] = 0.f;

  gemm_tile_loop(wl, xs, tid, lane, o0, acc,
    [&](int k0) {
      for (int f = tid; f < 2048; f += 256) {
        int pl = f >> 5, kk = f & 31;
        int row = (ph * 4 + (pl >> 4)) * 64 + wx * 16 + (pl & 15);
        xs[kk * 66 + pl] = t[((size_t)b * 4096 + row) * 192 + k0 + kk];
      }
    },
    [&](int k, int oc) { return srt[(size_t)k * 192 + oc]; });

#pragma unroll
  for (int j = 0; j < 48; ++j) {
    float gv = gelu_exact(acc[j] + sb[o0 + j]);
    gv += __shfl_xor(gv, 1, 64);
    gv += __shfl_xor(gv, 2, 64);
    gv += __shfl_xor(gv, 16, 64);
    gv += __shfl_xor(gv, 32, 64);
    if ((lane & 51) == 0) {
      int cell = (lane >> 2) & 3;
      int p = ph * 16 + wx * 4 + cell;
      pooled[((size_t)b * 256 + p) * 192 + o0 + j] = gv * (1.f / 16.f);
    }
  }
}

// ---------------- pooled kv -> kp (l2-normed)/vp [b][h][m][24] ----------------
__global__ __launch_bounds__(256) void k_kvp(
    const float* __restrict__ pooled, const float* __restrict__ kvt, const float* __restrict__ kb_,
    float* __restrict__ kp, float* __restrict__ vp) {
  __shared__ __align__(16) float wl[32 * 192];
  __shared__ float xs[32 * 66];
  const int tid = threadIdx.x;
  const int lane = tid & 63;
  const int wv = __builtin_amdgcn_readfirstlane(tid >> 6);
  const int r0 = blockIdx.x * 64;
  const int o0 = wv * 48;
  const int row = r0 + lane;
  const int b = row >> 8;
  const int m = row & 255;
  for (int s = 0; s < 2; ++s) {
    float acc[48];
#pragma unroll
    for (int j = 0; j < 48; ++j) acc[j] = 0.f;

    gemm_tile_loop(wl, xs, tid, lane, o0, acc,
      [&](int k0) {
        for (int f = tid; f < 2048; f += 256) {
          int nl = f >> 5, kk = f & 31;
          xs[kk * 66 + nl] = pooled[(size_t)(r0 + nl) * 192 + k0 + kk];
        }
      },
      [&](int k, int oc) { return kvt[(size_t)k * 384 + s * 192 + oc]; });

    const int ob = s * 192 + o0;
#pragma unroll
    for (int hl = 0; hl < 2; ++hl) {
      int hh = 2 * wv + hl;
      if (s == 0) {
        float sumsq = 0.f;
#pragma unroll
        for (int d = 0; d < 24; ++d) {
          float v = acc[hl * 24 + d] + kb_[ob + hl * 24 + d];
          sumsq += v * v;
        }
        float rn = 1.f / fmaxf(sqrtf(sumsq), 1e-12f);
#pragma unroll
        for (int d = 0; d < 24; ++d)
          kp[(((size_t)(b * 8 + hh)) * 256 + m) * 24 + d] =
              (acc[hl * 24 + d] + kb_[ob + hl * 24 + d]) * rn;
      } else {
#pragma unroll
        for (int d = 0; d < 24; ++d)
          vp[(((size_t)(b * 8 + hh)) * 256 + m) * 24 + d] =
              acc[hl * 24 + d] + kb_[ob + hl * 24 + d];
      }
    }
    __syncthreads();
  }
}

// ---------------- cpb MLP: (T,2) -> (T,8) ----------------
__global__ __launch_bounds__(256) void k_cpb(
    const float* __restrict__ coords, const float* __restrict__ c1w,
    const float* __restrict__ c1b, const float* __restrict__ c2w,
    const float* __restrict__ c2b, float* __restrict__ cpb, int T) {
  int i = blockIdx.x * 256 + threadIdx.x;
  if (i >= T) return;
  float x0 = coords[2 * i], y0 = coords[2 * i + 1];
  float a[8];
#pragma unroll
  for (int h = 0; h < 8; ++h) a[h] = c2b[h];
  for (int j = 0; j < 512; ++j) {
    float hv = fmaxf(c1w[2 * j] * x0 + c1w[2 * j + 1] * y0 + c1b[j], 0.f);
#pragma unroll
    for (int h = 0; h < 8; ++h) a[h] += hv * c2w[h * 512 + j];
  }
#pragma unroll
  for (int h = 0; h < 8; ++h) cpb[(size_t)i * 8 + h] = a[h];
}

// ---------------- pool bias gather: bt[h][m][n] ----------------
__global__ __launch_bounds__(256) void k_bias(
    const int* __restrict__ rel, const float* __restrict__ cpb, float* __restrict__ bt) {
  int n = blockIdx.x * 256 + threadIdx.x;
  int m = blockIdx.y;
  int idx = rel[(size_t)n * 256 + m];
  const float4* c4 = (const float4*)(cpb + (size_t)idx * 8);
  float4 A = c4[0], Bv = c4[1];
  float vals[8] = {A.x, A.y, A.z, A.w, Bv.x, Bv.y, Bv.z, Bv.w};
#pragma unroll
  for (int h = 0; h < 8; ++h)
    bt[((size_t)(h * 256 + m)) * 4096 + n] = vals[h];
}

// ---------------- fused attention ----------------
__global__ __launch_bounds__(256) void k_attn(
    const float* __restrict__ qs_g, const float* __restrict__ qn_g,
    const float* __restrict__ kmap, const float* __restrict__ kp, const float* __restrict__ vp,
    const float* __restrict__ bt, const float* __restrict__ rpb,
    const float* __restrict__ lt, const float* __restrict__ lb,
    float* __restrict__ ctx) {
  const int tid = threadIdx.x;
  const int lane = tid & 63;
  const int wv = __builtin_amdgcn_readfirstlane(tid >> 6);
  const int h = blockIdx.y;
  const int b = blockIdx.z;
  const int n = blockIdx.x * 256 + wv * 64 + lane;
  const int hpix = __builtin_amdgcn_readfirstlane(n >> 6);
  const int wpix = n & 63;
  const float SHIFT = 15.f;

  float qsv[24], qnv[24];
  const float* qsb = qs_g + ((size_t)(b * 8 + h) * 24) * 4096 + n;
  const float* qnb = qn_g + ((size_t)(b * 8 + h) * 24) * 4096 + n;
#pragma unroll
  for (int d = 0; d < 24; ++d) {
    qsv[d] = qsb[(size_t)d * 4096];
    qnv[d] = qnb[(size_t)d * 4096];
  }

  const float* ltp = lt + h * 216;
  const float* lbp = lb + h * 9;
  const float* rpp = rpb + h * 9;
  float wlv[9];
#pragma unroll
  for (int l = 0; l < 9; ++l) {
    float a0 = 0, a1 = 0, a2 = 0;
#pragma unroll
    for (int d = 0; d < 24; d += 3) {
      a0 += qnv[d] * ltp[d * 9 + l];
      a1 += qnv[d + 1] * ltp[(d + 1) * 9 + l];
      a2 += qnv[d + 2] * ltp[(d + 2) * 9 + l];
    }
    wlv[l] = a0 + a1 + a2 + lbp[l];
  }

  float ctxA[24], ctxB[24], ctxP[24];
#pragma unroll
  for (int d = 0; d < 24; ++d) { ctxA[d] = 0.f; ctxB[d] = 0.f; ctxP[d] = 0.f; }
  float S = 0.f;

  const float* kbase = kmap + ((size_t)b * 384 + h * 24) * 4096;
#pragma unroll
  for (int l = 0; l < 9; ++l) {
    const int dh = l / 3 - 1, dw = l % 3 - 1;
    const int hp = hpix + dh;
    if (hp < 0 || hp >= 64) continue;
    const int wp2 = wpix + dw;
    const bool okw = (wp2 >= 0) && (wp2 < 64);
    const int nn = (hp << 6) + wp2;
    const float* kb = kbase + nn;
    const float* vb = kb + (size_t)192 * 4096;
    float d0 = 0, d1 = 0, d2 = 0, d3 = 0;
#pragma unroll
    for (int d = 0; d < 24; d += 4) {
      d0 += qsv[d] * kb[(size_t)d * 4096];
      d1 += qsv[d + 1] * kb[(size_t)(d + 1) * 4096];
      d2 += qsv[d + 2] * kb[(size_t)(d + 2) * 4096];
      d3 += qsv[d + 3] * kb[(size_t)(d + 3) * 4096];
    }
    float p = okw ? __expf((d0 + d1) + (d2 + d3) + rpp[l] - SHIFT) : 0.f;
    S += p;
    float wll = wlv[l];
#pragma unroll
    for (int d = 0; d < 24; ++d) {
      float vv = okw ? vb[(size_t)d * 4096] : 0.f;
      ctxA[d] += wll * vv;
      ctxB[d] += p * vv;
    }
  }

  const float* kpb = kp + (size_t)(b * 8 + h) * 256 * 24;
  const float* vpb = vp + (size_t)(b * 8 + h) * 256 * 24;
  const float* bb = bt + (size_t)(h * 256) * 4096 + n;
#pragma unroll 2
  for (int m = 0; m < 256; ++m) {
    const float* kr = kpb + m * 24;
    const float* vr = vpb + m * 24;
    float d0 = 0, d1 = 0, d2 = 0, d3 = 0;
#pragma unroll
    for (int d = 0; d < 24; d += 4) {
      d0 += qsv[d] * kr[d];
      d1 += qsv[d + 1] * kr[d + 1];
      d2 += qsv[d + 2] * kr[d + 2];
      d3 += qsv[d + 3] * kr[d + 3];
    }
    float p = __expf((d0 + d1) + (d2 + d3) + bb[(size_t)m * 4096] - SHIFT);
    S += p;
#pragma unroll
    for (int d = 0; d < 24; ++d) ctxP[d] += p * vr[d];
  }

  const float inv = 1.f / S;
  float* cb = ctx + ((size_t)(b * 8 + h) * 24) * 4096 + n;
#pragma unroll
  for (int d = 0; d < 24; ++d)
    cb[(size_t)d * 4096] = ctxA[d] + (ctxB[d] + ctxP[d]) * inv;
}

// ---------------- proj + output LN, out[b][o][n] f32 ----------------
__global__ __launch_bounds__(256) void k_proj(
    const float* __restrict__ ctx, const float* __restrict__ pjt, const float* __restrict__ pb,
    const float* __restrict__ g, const float* __restrict__ be,
    float* __restrict__ out) {
  __shared__ __align__(16) float wl[32 * 192];
  __shared__ float xs[32 * 66];
  __shared__ float red[2][4][64];
  const int tid = threadIdx.x;
  const int lane = tid & 63;
  const int wv = __builtin_amdgcn_readfirstlane(tid >> 6);
  const int n0 = blockIdx.x * 64;
  const int b = blockIdx.y;
  const int o0 = wv * 48;
  float acc[48];
#pragma unroll
  for (int j = 0; j < 48; ++j) acc[j] = 0.f;

  gemm_tile_loop(wl, xs, tid, lane, o0, acc,
    [&](int k0) {
      for (int f = tid; f < 2048; f += 256) {
        int kk = f >> 6, nl = f & 63;
        xs[kk * 66 + nl] = ctx[((size_t)b * 192 + k0 + kk) * 4096 + n0 + nl];
      }
    },
    [&](int k, int oc) { return pjt[(size_t)k * 192 + oc]; });

  float s = 0, sq = 0;
#pragma unroll
  for (int j = 0; j < 48; ++j) {
    acc[j] += pb[o0 + j];
    s += acc[j];
    sq += acc[j] * acc[j];
  }
  red[0][wv][lane] = s;
  red[1][wv][lane] = sq;
  __syncthreads();
  float st = red[0][0][lane] + red[0][1][lane] + red[0][2][lane] + red[0][3][lane];
  float sqt = red[1][0][lane] + red[1][1][lane] + red[1][2][lane] + red[1][3][lane];
  float mean = st * (1.f / 192.f);
  float var = sqt * (1.f / 192.f) - mean * mean;
  float rstd = rsqrtf(var + 1e-5f);
#pragma unroll
  for (int j = 0; j < 48; ++j) {
    int o = o0 + j;
    out[((size_t)b * 192 + o) * 4096 + n0 + lane] = (acc[j] - mean) * rstd * g[o] + be[o];
  }
}

// ---------------- host launcher ----------------
extern "C" void kernel_launch(void* const* d_in, const int* in_sizes, int n_in,
                              void* d_out, int out_size, void* d_ws, size_t ws_size,
                              hipStream_t stream) {
  float* w = (float*)d_ws;

  const float* x      = (const float*)d_in[0];
  const float* pe_w   = (const float*)d_in[1];
  const float* pe_b   = (const float*)d_in[2];
  const float* peln_g = (const float*)d_in[3];
  const float* peln_b = (const float*)d_in[4];
  const float* q_w    = (const float*)d_in[5];
  const float* q_b    = (const float*)d_in[6];
  const float* kv_w   = (const float*)d_in[7];
  const float* kv_b   = (const float*)d_in[8];
  const float* sr_w   = (const float*)d_in[9];
  const float* sr_b   = (const float*)d_in[10];
  const float* norm_g = (const float*)d_in[11];
  const float* norm_b = (const float*)d_in[12];
  const float* cpb1w  = (const float*)d_in[13];
  const float* cpb1b  = (const float*)d_in[14];
  const float* cpb2w  = (const float*)d_in[15];
  const float* cpb2b  = (const float*)d_in[16];
  const float* rpb    = (const float*)d_in[17];
  const float* lt     = (const float*)d_in[18];
  const float* lb     = (const float*)d_in[19];
  const float* qe     = (const float*)d_in[20];
  const float* temp   = (const float*)d_in[21];
  const float* proj_w = (const float*)d_in[22];
  const float* proj_b = (const float*)d_in[23];
  const float* oln_g  = (const float*)d_in[24];
  const float* oln_b  = (const float*)d_in[25];
  const int*   rel    = (const int*)d_in[26];
  const float* coords = (const float*)d_in[27];
  const float* ss     = (const float*)d_in[28];

  dim3 blk(256);
  k_wt_conv<<<dim3(1296), blk, 0, stream>>>(pe_w, w + OFF_WTC);
  k_wt_gen<<<dim3(144), blk, 0, stream>>>(q_w, w + OFF_QT, 192, 192);
  k_wt_gen<<<dim3(288), blk, 0, stream>>>(kv_w, w + OFF_KVT, 384, 192);
  k_wt_gen<<<dim3(144), blk, 0, stream>>>(sr_w, w + OFF_SRT, 192, 192);

  k_conv<<<dim3(64, 4), blk, 0, stream>>>(x, w + OFF_WTC, pe_b, w + OFF_T);
  k_ln_rows<<<dim3(4096), blk, 0, stream>>>(w + OFF_T, peln_g, peln_b, 16384);
  k_q<<<dim3(64, 4), blk, 0, stream>>>(w + OFF_T, w + OFF_QT, q_b, qe, temp, ss,
      w + OFF_QN, w + OFF_QS);
  k_kv<<<dim3(64, 4), blk, 0, stream>>>(w + OFF_T, w + OFF_KVT, kv_b, w + OFF_KMAP);
  k_srpool<<<dim3(4, 16, 4), blk, 0, stream>>>(w + OFF_T, w + OFF_SRT, sr_b, w + OFF_POOL);
  k_ln_rows<<<dim3(256), blk, 0, stream>>>(w + OFF_POOL, norm_g, norm_b, 1024);
  k_kvp<<<dim3(16), blk, 0, stream>>>(w + OFF_POOL, w + OFF_KVT, kv_b, w + OFF_KP, w + OFF_VP);
  int T = in_sizes[27] / 2;
  k_cpb<<<dim3((T + 255) / 256), blk, 0, stream>>>(coords, cpb1w, cpb1b, cpb2w, cpb2b,
      w + OFF_CPB, T);
  k_bias<<<dim3(16, 256), blk, 0, stream>>>(rel, w + OFF_CPB, w + OFF_BIAS);
  k_attn<<<dim3(16, 8, 4), blk, 0, stream>>>(w + OFF_QS, w + OFF_QN, w + OFF_KMAP,
      w + OFF_KP, w + OFF_VP, w + OFF_BIAS, rpb, lt, lb, w + OFF_CTX);
  k_wt_gen<<<dim3(144), blk, 0, stream>>>(proj_w, w + OFF_PJT, 192, 192);
  k_proj<<<dim3(64, 4), blk, 0, stream>>>(w + OFF_CTX, w + OFF_PJT, proj_b, oln_g, oln_b,
      (float*)d_out);
}

// Round 7
// 834.047 us; speedup vs baseline: 3.6917x; 1.5893x over previous
//
#include <hip/hip_runtime.h>
#include <stdint.h>

// B=4, DIM=192, H=W=64, N=4096, HEADS=8, HD=24, SR=4, PLEN=256, LL=9
// All inputs f32, output f32.

// ---------------- workspace layout (floats) ----------------
constexpr size_t OFF_T    = 0;          // (B,N,192)
constexpr size_t OFF_KMAP = 3145728;    // (B,384,N)
constexpr size_t OFF_QN   = 9437184;    // (B,8,24,N)
constexpr size_t OFF_QS   = 12582912;   // (B,8,24,N)
constexpr size_t OFF_CTX  = 15728640;   // (B,8,24,N)  (early: scratch for W transposes)
constexpr size_t OFF_POOL = 18874368;   // (B,256,192)
constexpr size_t OFF_KP   = 19070976;   // (B,8,256,24)
constexpr size_t OFF_VP   = 19267584;   // (B,8,256,24)
constexpr size_t OFF_CPB  = 19464192;   // (T,8)
constexpr size_t OFF_BIAS = 19595264;   // (8,256,4096) -> end 27983872 floats (~112 MB)
// transposed weights live in regions that are dead at their time of use:
constexpr size_t OFF_WTC  = OFF_CTX;              // conv wt [1728][192]
constexpr size_t OFF_QT   = OFF_CTX + 331776;     // [192][192]
constexpr size_t OFF_KVT  = OFF_CTX + 368640;     // [192][384]
constexpr size_t OFF_SRT  = OFF_CTX + 442368;     // [192][192]
constexpr size_t OFF_PJT  = OFF_KMAP;             // [192][192], created AFTER attn

// ---------------- weight transposes ----------------
__global__ __launch_bounds__(256) void k_wt_conv(const float* __restrict__ pw,
                                                 float* __restrict__ wt) {
  int i = blockIdx.x * 256 + threadIdx.x;
  if (i >= 331776) return;
  int oc = i % 192, k = i / 192;
  wt[i] = pw[(size_t)oc * 1728 + k];
}
__global__ __launch_bounds__(256) void k_wt_gen(const float* __restrict__ src,
                                                float* __restrict__ dst, int O, int K) {
  int i = blockIdx.x * 256 + threadIdx.x;
  if (i >= O * K) return;
  int o = i % O, k = i / O;
  dst[i] = src[(size_t)o * K + k];
}

// ---------------- 3x3 conv, 48 oc per block; grid (64 h, 4 b, 4 ocq) ----------------
__global__ __launch_bounds__(256) void k_conv(
    const float* __restrict__ x, const float* __restrict__ wtc,
    const float* __restrict__ bf, float* __restrict__ t) {
  __shared__ __align__(16) float wl[72 * 48];   // 13.8 KB  [k][oc48]
  __shared__ float xl[8 * 198];                 // 6.2 KB   [ii][r][wp 0..65]
  const int tid = threadIdx.x;
  const int lane = tid & 63;
  const int wv = __builtin_amdgcn_readfirstlane(tid >> 6);
  const int h = blockIdx.x;
  const int b = blockIdx.y;
  const int obase = blockIdx.z * 48;
  const int ow = obase + wv * 12;

  float acc[12];
#pragma unroll
  for (int j = 0; j < 12; ++j) acc[j] = 0.f;

  for (int ic0 = 0; ic0 < 24; ++ic0) {
    __syncthreads();
    for (int f = tid; f < 1584; f += 256) {
      int ii = f / 198;
      int rem = f - ii * 198;
      int r = rem / 66;
      int wp = rem - r * 66;
      int hh = h + r - 1, ww = wp - 1;
      float v = 0.f;
      if (hh >= 0 && hh < 64 && ww >= 0 && ww < 64)
        v = x[((size_t)(b * 192 + ic0 * 8 + ii) << 12) + (hh << 6) + ww];
      xl[ii * 198 + r * 66 + wp] = v;
    }
    for (int f4 = tid; f4 < 864; f4 += 256) {
      int kk = f4 / 12, j = f4 - kk * 12;
      ((float4*)wl)[f4] =
          ((const float4*)(wtc + (size_t)(ic0 * 72 + kk) * 192 + obase))[j];
    }
    __syncthreads();
#pragma unroll 1
    for (int ii = 0; ii < 8; ++ii) {
#pragma unroll
      for (int r = 0; r < 3; ++r) {
        const float* xrow = &xl[ii * 198 + r * 66 + lane];
        float xv0 = xrow[0], xv1 = xrow[1], xv2 = xrow[2];
#pragma unroll
        for (int kw = 0; kw < 3; ++kw) {
          float xv = (kw == 0) ? xv0 : ((kw == 1) ? xv1 : xv2);
          const float4* wrow = (const float4*)&wl[(ii * 9 + r * 3 + kw) * 48 + wv * 12];
#pragma unroll
          for (int j4 = 0; j4 < 3; ++j4) {
            float4 w4 = wrow[j4];
            acc[j4 * 4 + 0] += xv * w4.x;
            acc[j4 * 4 + 1] += xv * w4.y;
            acc[j4 * 4 + 2] += xv * w4.z;
            acc[j4 * 4 + 3] += xv * w4.w;
          }
        }
      }
    }
  }
  float* outp = t + ((size_t)b * 4096 + h * 64 + lane) * 192 + ow;
#pragma unroll
  for (int j4 = 0; j4 < 3; ++j4) {
    float4 v;
    v.x = acc[j4 * 4 + 0] + bf[ow + j4 * 4 + 0];
    v.y = acc[j4 * 4 + 1] + bf[ow + j4 * 4 + 1];
    v.z = acc[j4 * 4 + 2] + bf[ow + j4 * 4 + 2];
    v.w = acc[j4 * 4 + 3] + bf[ow + j4 * 4 + 3];
    ((float4*)outp)[j4] = v;
  }
}

// ---------------- LN over 192 channels, in-place (wave per row) ----------------
__global__ __launch_bounds__(256) void k_ln_rows(float* __restrict__ data,
    const float* __restrict__ g, const float* __restrict__ be, int rows) {
  int lane = threadIdx.x & 63;
  int wv = threadIdx.x >> 6;
  int row = blockIdx.x * 4 + wv;
  if (row >= rows) return;
  float* p = data + (size_t)row * 192;
  float v0 = p[lane], v1 = p[lane + 64], v2 = p[lane + 128];
  float s = v0 + v1 + v2;
  float sq = v0 * v0 + v1 * v1 + v2 * v2;
#pragma unroll
  for (int m = 32; m >= 1; m >>= 1) {
    s += __shfl_xor(s, m, 64);
    sq += __shfl_xor(sq, m, 64);
  }
  float mean = s * (1.f / 192.f);
  float var = sq * (1.f / 192.f) - mean * mean;
  float rstd = rsqrtf(var + 1e-5f);
  p[lane]       = (v0 - mean) * rstd * g[lane]       + be[lane];
  p[lane + 64]  = (v1 - mean) * rstd * g[lane + 64]  + be[lane + 64];
  p[lane + 128] = (v2 - mean) * rstd * g[lane + 128] + be[lane + 128];
}

// ======== GEMM tile core: xs[kk][px(66)], wl[kk][OCB], acc OCB/4 per lane ========
template <int OCB, typename StageX>
__device__ __forceinline__ void gemm_tiles(
    float* __restrict__ wl, float* __restrict__ xs, int tid, int lane, int wv,
    const float* __restrict__ wt, int ostr, int obase,
    float (&acc)[OCB / 4], StageX stage_x) {
  constexpr int NPF4 = OCB / 4;    // float4 per k-row
  constexpr int NW4 = OCB / 16;    // float4 per wave slice
  for (int kt = 0; kt < 6; ++kt) {
    const int k0 = kt * 32;
    __syncthreads();
    stage_x(k0);
    for (int f4 = tid; f4 < 32 * NPF4; f4 += 256) {
      int kk = f4 / NPF4, j = f4 - kk * NPF4;
      ((float4*)wl)[f4] = ((const float4*)(wt + (size_t)(k0 + kk) * ostr + obase))[j];
    }
    __syncthreads();
#pragma unroll 4
    for (int kk = 0; kk < 32; ++kk) {
      float xv = xs[kk * 66 + lane];
      const float4* wrow = (const float4*)&wl[kk * OCB + wv * NPF4];
#pragma unroll
      for (int j4 = 0; j4 < NW4; ++j4) {
        float4 w4 = wrow[j4];
        acc[j4 * 4 + 0] += xv * w4.x;
        acc[j4 * 4 + 1] += xv * w4.y;
        acc[j4 * 4 + 2] += xv * w4.z;
        acc[j4 * 4 + 3] += xv * w4.w;
      }
    }
  }
}

// ---------------- q GEMM (96 oc = 4 heads/block) -> l2norm -> scaled ----------------
__global__ __launch_bounds__(256) void k_q(
    const float* __restrict__ t, const float* __restrict__ qt, const float* __restrict__ qb,
    const float* __restrict__ qe, const float* __restrict__ tmp, const float* __restrict__ ss,
    float* __restrict__ qno, float* __restrict__ qso) {
  __shared__ __align__(16) float wl[32 * 96];
  __shared__ float xs[32 * 66];
  const int tid = threadIdx.x;
  const int lane = tid & 63;
  const int wv = __builtin_amdgcn_readfirstlane(tid >> 6);
  const int n0 = blockIdx.x * 64;
  const int b = blockIdx.y;
  const int obase = blockIdx.z * 96;
  const int hh = blockIdx.z * 4 + wv;
  const int oc0 = obase + wv * 24;
  float acc[24];
#pragma unroll
  for (int j = 0; j < 24; ++j) acc[j] = 0.f;

  gemm_tiles<96>(wl, xs, tid, lane, wv, qt, 192, obase, acc,
    [&](int k0) {
      for (int f = tid; f < 2048; f += 256) {
        int nl = f >> 5, kk = f & 31;
        xs[kk * 66 + nl] = t[((size_t)b * 4096 + n0 + nl) * 192 + k0 + kk];
      }
    });

  const int n = n0 + lane;
  float ssv = ss[n];
  float sumsq = 0.f;
#pragma unroll
  for (int d = 0; d < 24; ++d) {
    float v = acc[d] + qb[oc0 + d];
    sumsq += v * v;
  }
  float rn = 1.f / fmaxf(sqrtf(sumsq), 1e-12f);
  float sp = log1pf(__expf(tmp[hh]));
#pragma unroll
  for (int d = 0; d < 24; ++d) {
    float qv = (acc[d] + qb[oc0 + d]) * rn;
    size_t o = ((size_t)(b * 8 + hh) * 24 + d) * 4096 + n;
    qno[o] = qv;
    qso[o] = (qv + qe[hh * 24 + d]) * sp * ssv;
  }
}

// ---------------- kv GEMM (96 of 384 oc/block) -> kmap[b][c][n] ----------------
__global__ __launch_bounds__(256) void k_kv(
    const float* __restrict__ t, const float* __restrict__ kvt, const float* __restrict__ kb_,
    float* __restrict__ kmap) {
  __shared__ __align__(16) float wl[32 * 96];
  __shared__ float xs[32 * 66];
  const int tid = threadIdx.x;
  const int lane = tid & 63;
  const int wv = __builtin_amdgcn_readfirstlane(tid >> 6);
  const int n0 = blockIdx.x * 64;
  const int b = blockIdx.y;
  const int obase = blockIdx.z * 96;
  const int oc0 = obase + wv * 24;
  const int n = n0 + lane;
  float acc[24];
#pragma unroll
  for (int j = 0; j < 24; ++j) acc[j] = 0.f;

  gemm_tiles<96>(wl, xs, tid, lane, wv, kvt, 384, obase, acc,
    [&](int k0) {
      for (int f = tid; f < 2048; f += 256) {
        int nl = f >> 5, kk = f & 31;
        xs[kk * 66 + nl] = t[((size_t)b * 4096 + n0 + nl) * 192 + k0 + kk];
      }
    });

  if (oc0 < 192) {   // k section: l2-normalize per head (oc0 is head-aligned)
    float sumsq = 0.f;
#pragma unroll
    for (int d = 0; d < 24; ++d) {
      float v = acc[d] + kb_[oc0 + d];
      sumsq += v * v;
    }
    float rn = 1.f / fmaxf(sqrtf(sumsq), 1e-12f);
#pragma unroll
    for (int d = 0; d < 24; ++d)
      kmap[((size_t)b * 384 + oc0 + d) * 4096 + n] = (acc[d] + kb_[oc0 + d]) * rn;
  } else {           // v section: raw
#pragma unroll
    for (int d = 0; d < 24; ++d)
      kmap[((size_t)b * 384 + oc0 + d) * 4096 + n] = acc[d] + kb_[oc0 + d];
  }
}

// ---------------- sr GEMM (48 oc/block) + exact gelu + 4x4 mean-pool ----------------
__device__ __forceinline__ float gelu_exact(float v) {
  float u = v * 0.70710678118654752f;
  float a = fabsf(u);
  float tt = 1.f / (1.f + 0.3275911f * a);
  float poly = ((((1.061405429f * tt - 1.453152027f) * tt + 1.421413741f) * tt
                 - 0.284496736f) * tt + 0.254829592f) * tt;
  float erfa = 1.f - poly * __expf(-a * a);
  float erfv = (u < 0.f) ? -erfa : erfa;
  return 0.5f * v * (1.f + erfv);
}

__global__ __launch_bounds__(256) void k_srpool(
    const float* __restrict__ t, const float* __restrict__ srt, const float* __restrict__ sb,
    float* __restrict__ pooled) {
  __shared__ __align__(16) float wl[32 * 48];
  __shared__ float xs[32 * 66];
  const int tid = threadIdx.x;
  const int lane = tid & 63;
  const int wv = __builtin_amdgcn_readfirstlane(tid >> 6);
  const int wx = blockIdx.x & 3;        // 0..3
  const int obase = (blockIdx.x >> 2) * 48;
  const int ph = blockIdx.y;            // 0..15
  const int b = blockIdx.z;
  const int oc0 = obase + wv * 12;
  float acc[12];
#pragma unroll
  for (int j = 0; j < 12; ++j) acc[j] = 0.f;

  gemm_tiles<48>(wl, xs, tid, lane, wv, srt, 192, obase, acc,
    [&](int k0) {
      for (int f = tid; f < 2048; f += 256) {
        int pl = f >> 5, kk = f & 31;
        int row = (ph * 4 + (pl >> 4)) * 64 + wx * 16 + (pl & 15);
        xs[kk * 66 + pl] = t[((size_t)b * 4096 + row) * 192 + k0 + kk];
      }
    });

#pragma unroll
  for (int j = 0; j < 12; ++j) {
    float gv = gelu_exact(acc[j] + sb[oc0 + j]);
    gv += __shfl_xor(gv, 1, 64);
    gv += __shfl_xor(gv, 2, 64);
    gv += __shfl_xor(gv, 16, 64);
    gv += __shfl_xor(gv, 32, 64);
    if ((lane & 51) == 0) {
      int cell = (lane >> 2) & 3;
      int p = ph * 16 + wx * 4 + cell;
      pooled[((size_t)b * 256 + p) * 192 + oc0 + j] = gv * (1.f / 16.f);
    }
  }
}

// ---------------- pooled kv (96 of 384 oc/block) -> kp/vp [b][h][m][24] ----------------
__global__ __launch_bounds__(256) void k_kvp(
    const float* __restrict__ pooled, const float* __restrict__ kvt, const float* __restrict__ kb_,
    float* __restrict__ kp, float* __restrict__ vp) {
  __shared__ __align__(16) float wl[32 * 96];
  __shared__ float xs[32 * 66];
  const int tid = threadIdx.x;
  const int lane = tid & 63;
  const int wv = __builtin_amdgcn_readfirstlane(tid >> 6);
  const int r0 = blockIdx.x * 64;
  const int obase = blockIdx.y * 96;
  const int oc0 = obase + wv * 24;
  const int row = r0 + lane;
  const int b = row >> 8;
  const int m = row & 255;
  float acc[24];
#pragma unroll
  for (int j = 0; j < 24; ++j) acc[j] = 0.f;

  gemm_tiles<96>(wl, xs, tid, lane, wv, kvt, 384, obase, acc,
    [&](int k0) {
      for (int f = tid; f < 2048; f += 256) {
        int nl = f >> 5, kk = f & 31;
        xs[kk * 66 + nl] = pooled[(size_t)(r0 + nl) * 192 + k0 + kk];
      }
    });

  if (oc0 < 192) {
    int hh = oc0 / 24;
    float sumsq = 0.f;
#pragma unroll
    for (int d = 0; d < 24; ++d) {
      float v = acc[d] + kb_[oc0 + d];
      sumsq += v * v;
    }
    float rn = 1.f / fmaxf(sqrtf(sumsq), 1e-12f);
#pragma unroll
    for (int d = 0; d < 24; ++d)
      kp[(((size_t)(b * 8 + hh)) * 256 + m) * 24 + d] = (acc[d] + kb_[oc0 + d]) * rn;
  } else {
    int hh = (oc0 - 192) / 24;
#pragma unroll
    for (int d = 0; d < 24; ++d)
      vp[(((size_t)(b * 8 + hh)) * 256 + m) * 24 + d] = acc[d] + kb_[oc0 + d];
  }
}

// ---------------- cpb MLP: (T,2) -> (T,8) ----------------
__global__ __launch_bounds__(256) void k_cpb(
    const float* __restrict__ coords, const float* __restrict__ c1w,
    const float* __restrict__ c1b, const float* __restrict__ c2w,
    const float* __restrict__ c2b, float* __restrict__ cpb, int T) {
  int i = blockIdx.x * 256 + threadIdx.x;
  if (i >= T) return;
  float x0 = coords[2 * i], y0 = coords[2 * i + 1];
  float a[8];
#pragma unroll
  for (int h = 0; h < 8; ++h) a[h] = c2b[h];
  for (int j = 0; j < 512; ++j) {
    float hv = fmaxf(c1w[2 * j] * x0 + c1w[2 * j + 1] * y0 + c1b[j], 0.f);
#pragma unroll
    for (int h = 0; h < 8; ++h) a[h] += hv * c2w[h * 512 + j];
  }
#pragma unroll
  for (int h = 0; h < 8; ++h) cpb[(size_t)i * 8 + h] = a[h];
}

// ---------------- pool bias gather: bt[h][m][n] ----------------
__global__ __launch_bounds__(256) void k_bias(
    const int* __restrict__ rel, const float* __restrict__ cpb, float* __restrict__ bt) {
  int n = blockIdx.x * 256 + threadIdx.x;
  int m = blockIdx.y;
  int idx = rel[(size_t)n * 256 + m];
  const float4* c4 = (const float4*)(cpb + (size_t)idx * 8);
  float4 A = c4[0], Bv = c4[1];
  float vals[8] = {A.x, A.y, A.z, A.w, Bv.x, Bv.y, Bv.z, Bv.w};
#pragma unroll
  for (int h = 0; h < 8; ++h)
    bt[((size_t)(h * 256 + m)) * 4096 + n] = vals[h];
}

// ---------------- fused attention ----------------
__global__ __launch_bounds__(256) void k_attn(
    const float* __restrict__ qs_g, const float* __restrict__ qn_g,
    const float* __restrict__ kmap, const float* __restrict__ kp, const float* __restrict__ vp,
    const float* __restrict__ bt, const float* __restrict__ rpb,
    const float* __restrict__ lt, const float* __restrict__ lb,
    float* __restrict__ ctx) {
  const int tid = threadIdx.x;
  const int lane = tid & 63;
  const int wv = __builtin_amdgcn_readfirstlane(tid >> 6);
  const int h = blockIdx.y;
  const int b = blockIdx.z;
  const int n = blockIdx.x * 256 + wv * 64 + lane;
  const int hpix = __builtin_amdgcn_readfirstlane(n >> 6);
  const int wpix = n & 63;
  const float SHIFT = 15.f;

  float qsv[24], qnv[24];
  const float* qsb = qs_g + ((size_t)(b * 8 + h) * 24) * 4096 + n;
  const float* qnb = qn_g + ((size_t)(b * 8 + h) * 24) * 4096 + n;
#pragma unroll
  for (int d = 0; d < 24; ++d) {
    qsv[d] = qsb[(size_t)d * 4096];
    qnv[d] = qnb[(size_t)d * 4096];
  }

  const float* ltp = lt + h * 216;
  const float* lbp = lb + h * 9;
  const float* rpp = rpb + h * 9;
  float wlv[9];
#pragma unroll
  for (int l = 0; l < 9; ++l) {
    float a0 = 0, a1 = 0, a2 = 0;
#pragma unroll
    for (int d = 0; d < 24; d += 3) {
      a0 += qnv[d] * ltp[d * 9 + l];
      a1 += qnv[d + 1] * ltp[(d + 1) * 9 + l];
      a2 += qnv[d + 2] * ltp[(d + 2) * 9 + l];
    }
    wlv[l] = a0 + a1 + a2 + lbp[l];
  }

  float ctxA[24], ctxB[24], ctxP[24];
#pragma unroll
  for (int d = 0; d < 24; ++d) { ctxA[d] = 0.f; ctxB[d] = 0.f; ctxP[d] = 0.f; }
  float S = 0.f;

  const float* kbase = kmap + ((size_t)b * 384 + h * 24) * 4096;
#pragma unroll
  for (int l = 0; l < 9; ++l) {
    const int dh = l / 3 - 1, dw = l % 3 - 1;
    const int hp = hpix + dh;
    if (hp < 0 || hp >= 64) continue;
    const int wp2 = wpix + dw;
    const bool okw = (wp2 >= 0) && (wp2 < 64);
    const int nn = (hp << 6) + wp2;
    const float* kb = kbase + nn;
    const float* vb = kb + (size_t)192 * 4096;
    float d0 = 0, d1 = 0, d2 = 0, d3 = 0;
#pragma unroll
    for (int d = 0; d < 24; d += 4) {
      d0 += qsv[d] * kb[(size_t)d * 4096];
      d1 += qsv[d + 1] * kb[(size_t)(d + 1) * 4096];
      d2 += qsv[d + 2] * kb[(size_t)(d + 2) * 4096];
      d3 += qsv[d + 3] * kb[(size_t)(d + 3) * 4096];
    }
    float p = okw ? __expf((d0 + d1) + (d2 + d3) + rpp[l] - SHIFT) : 0.f;
    S += p;
    float wll = wlv[l];
#pragma unroll
    for (int d = 0; d < 24; ++d) {
      float vv = okw ? vb[(size_t)d * 4096] : 0.f;
      ctxA[d] += wll * vv;
      ctxB[d] += p * vv;
    }
  }

  const float* kpb = kp + (size_t)(b * 8 + h) * 256 * 24;
  const float* vpb = vp + (size_t)(b * 8 + h) * 256 * 24;
  const float* bb = bt + (size_t)(h * 256) * 4096 + n;
#pragma unroll 2
  for (int m = 0; m < 256; ++m) {
    const float* kr = kpb + m * 24;
    const float* vr = vpb + m * 24;
    float d0 = 0, d1 = 0, d2 = 0, d3 = 0;
#pragma unroll
    for (int d = 0; d < 24; d += 4) {
      d0 += qsv[d] * kr[d];
      d1 += qsv[d + 1] * kr[d + 1];
      d2 += qsv[d + 2] * kr[d + 2];
      d3 += qsv[d + 3] * kr[d + 3];
    }
    float p = __expf((d0 + d1) + (d2 + d3) + bb[(size_t)m * 4096] - SHIFT);
    S += p;
#pragma unroll
    for (int d = 0; d < 24; ++d) ctxP[d] += p * vr[d];
  }

  const float inv = 1.f / S;
  float* cb = ctx + ((size_t)(b * 8 + h) * 24) * 4096 + n;
#pragma unroll
  for (int d = 0; d < 24; ++d)
    cb[(size_t)d * 4096] = ctxA[d] + (ctxB[d] + ctxP[d]) * inv;
}

// ---------------- proj + output LN, out[b][o][n] f32 (unchanged structure) ----------------
__global__ __launch_bounds__(256) void k_proj(
    const float* __restrict__ ctx, const float* __restrict__ pjt, const float* __restrict__ pb,
    const float* __restrict__ g, const float* __restrict__ be,
    float* __restrict__ out) {
  __shared__ __align__(16) float wl[32 * 192];
  __shared__ float xs[32 * 66];
  __shared__ float red[2][4][64];
  const int tid = threadIdx.x;
  const int lane = tid & 63;
  const int wv = __builtin_amdgcn_readfirstlane(tid >> 6);
  const int n0 = blockIdx.x * 64;
  const int b = blockIdx.y;
  const int o0 = wv * 48;
  float acc[48];
#pragma unroll
  for (int j = 0; j < 48; ++j) acc[j] = 0.f;

  for (int kt = 0; kt < 6; ++kt) {
    const int k0 = kt * 32;
    __syncthreads();
    for (int f = tid; f < 2048; f += 256) {
      int kk = f >> 6, nl = f & 63;
      xs[kk * 66 + nl] = ctx[((size_t)b * 192 + k0 + kk) * 4096 + n0 + nl];
    }
    for (int f = tid; f < 6144; f += 256) {
      int kk = f / 192, oc = f - kk * 192;
      wl[f] = pjt[(size_t)(k0 + kk) * 192 + oc];
    }
    __syncthreads();
#pragma unroll 4
    for (int kk = 0; kk < 32; ++kk) {
      float xv = xs[kk * 66 + lane];
      const float4* wrow = (const float4*)&wl[kk * 192 + o0];
#pragma unroll
      for (int j4 = 0; j4 < 12; ++j4) {
        float4 w4 = wrow[j4];
        acc[j4 * 4 + 0] += xv * w4.x;
        acc[j4 * 4 + 1] += xv * w4.y;
        acc[j4 * 4 + 2] += xv * w4.z;
        acc[j4 * 4 + 3] += xv * w4.w;
      }
    }
  }

  float s = 0, sq = 0;
#pragma unroll
  for (int j = 0; j < 48; ++j) {
    acc[j] += pb[o0 + j];
    s += acc[j];
    sq += acc[j] * acc[j];
  }
  red[0][wv][lane] = s;
  red[1][wv][lane] = sq;
  __syncthreads();
  float st = red[0][0][lane] + red[0][1][lane] + red[0][2][lane] + red[0][3][lane];
  float sqt = red[1][0][lane] + red[1][1][lane] + red[1][2][lane] + red[1][3][lane];
  float mean = st * (1.f / 192.f);
  float var = sqt * (1.f / 192.f) - mean * mean;
  float rstd = rsqrtf(var + 1e-5f);
#pragma unroll
  for (int j = 0; j < 48; ++j) {
    int o = o0 + j;
    out[((size_t)b * 192 + o) * 4096 + n0 + lane] = (acc[j] - mean) * rstd * g[o] + be[o];
  }
}

// ---------------- host launcher ----------------
extern "C" void kernel_launch(void* const* d_in, const int* in_sizes, int n_in,
                              void* d_out, int out_size, void* d_ws, size_t ws_size,
                              hipStream_t stream) {
  float* w = (float*)d_ws;

  const float* x      = (const float*)d_in[0];
  const float* pe_w   = (const float*)d_in[1];
  const float* pe_b   = (const float*)d_in[2];
  const float* peln_g = (const float*)d_in[3];
  const float* peln_b = (const float*)d_in[4];
  const float* q_w    = (const float*)d_in[5];
  const float* q_b    = (const float*)d_in[6];
  const float* kv_w   = (const float*)d_in[7];
  const float* kv_b   = (const float*)d_in[8];
  const float* sr_w   = (const float*)d_in[9];
  const float* sr_b   = (const float*)d_in[10];
  const float* norm_g = (const float*)d_in[11];
  const float* norm_b = (const float*)d_in[12];
  const float* cpb1w  = (const float*)d_in[13];
  const float* cpb1b  = (const float*)d_in[14];
  const float* cpb2w  = (const float*)d_in[15];
  const float* cpb2b  = (const float*)d_in[16];
  const float* rpb    = (const float*)d_in[17];
  const float* lt     = (const float*)d_in[18];
  const float* lb     = (const float*)d_in[19];
  const float* qe     = (const float*)d_in[20];
  const float* temp   = (const float*)d_in[21];
  const float* proj_w = (const float*)d_in[22];
  const float* proj_b = (const float*)d_in[23];
  const float* oln_g  = (const float*)d_in[24];
  const float* oln_b  = (const float*)d_in[25];
  const int*   rel    = (const int*)d_in[26];
  const float* coords = (const float*)d_in[27];
  const float* ss     = (const float*)d_in[28];

  dim3 blk(256);
  k_wt_conv<<<dim3(1296), blk, 0, stream>>>(pe_w, w + OFF_WTC);
  k_wt_gen<<<dim3(144), blk, 0, stream>>>(q_w, w + OFF_QT, 192, 192);
  k_wt_gen<<<dim3(288), blk, 0, stream>>>(kv_w, w + OFF_KVT, 384, 192);
  k_wt_gen<<<dim3(144), blk, 0, stream>>>(sr_w, w + OFF_SRT, 192, 192);

  k_conv<<<dim3(64, 4, 4), blk, 0, stream>>>(x, w + OFF_WTC, pe_b, w + OFF_T);
  k_ln_rows<<<dim3(4096), blk, 0, stream>>>(w + OFF_T, peln_g, peln_b, 16384);
  k_q<<<dim3(64, 4, 2), blk, 0, stream>>>(w + OFF_T, w + OFF_QT, q_b, qe, temp, ss,
      w + OFF_QN, w + OFF_QS);
  k_kv<<<dim3(64, 4, 4), blk, 0, stream>>>(w + OFF_T, w + OFF_KVT, kv_b, w + OFF_KMAP);
  k_srpool<<<dim3(16, 16, 4), blk, 0, stream>>>(w + OFF_T, w + OFF_SRT, sr_b, w + OFF_POOL);
  k_ln_rows<<<dim3(256), blk, 0, stream>>>(w + OFF_POOL, norm_g, norm_b, 1024);
  k_kvp<<<dim3(16, 4), blk, 0, stream>>>(w + OFF_POOL, w + OFF_KVT, kv_b,
      w + OFF_KP, w + OFF_VP);
  int T = in_sizes[27] / 2;
  k_cpb<<<dim3((T + 255) / 256), blk, 0, stream>>>(coords, cpb1w, cpb1b, cpb2w, cpb2b,
      w + OFF_CPB, T);
  k_bias<<<dim3(16, 256), blk, 0, stream>>>(rel, w + OFF_CPB, w + OFF_BIAS);
  k_attn<<<dim3(16, 8, 4), blk, 0, stream>>>(w + OFF_QS, w + OFF_QN, w + OFF_KMAP,
      w + OFF_KP, w + OFF_VP, w + OFF_BIAS, rpb, lt, lb, w + OFF_CTX);
  k_wt_gen<<<dim3(144), blk, 0, stream>>>(proj_w, w + OFF_PJT, 192, 192);
  k_proj<<<dim3(64, 4), blk, 0, stream>>>(w + OFF_CTX, w + OFF_PJT, proj_b, oln_g, oln_b,
      (float*)d_out);
}

// Round 8
// 759.048 us; speedup vs baseline: 4.0565x; 1.0988x over previous
//
#include <hip/hip_runtime.h>
#include <stdint.h>

// B=4, DIM=192, H=W=64, N=4096, HEADS=8, HD=24, SR=4, PLEN=256, LL=9
// All inputs f32, output f32.

__device__ __forceinline__ float b2f(unsigned short u) {
  return __uint_as_float(((unsigned)u) << 16);
}
__device__ __forceinline__ unsigned short f2b(float f) {
  unsigned x = __float_as_uint(f);
  return (unsigned short)((x + 0x7fffu + ((x >> 16) & 1u)) >> 16);
}

// ---------------- workspace layout (floats) ----------------
constexpr size_t OFF_T    = 0;          // (B,N,192)
constexpr size_t OFF_KMAP = 3145728;    // (B,384,N)
constexpr size_t OFF_QN   = 9437184;    // (B,8,24,N); reused as pout (B,192,N) after attn
constexpr size_t OFF_QS   = 12582912;   // (B,8,24,N)
constexpr size_t OFF_CTX  = 15728640;   // (B,8,24,N)  (early: scratch for W transposes)
constexpr size_t OFF_POOL = 18874368;   // (B,256,192)
constexpr size_t OFF_KP   = 19070976;   // (B,8,256,24)
constexpr size_t OFF_VP   = 19267584;   // (B,8,256,24)
constexpr size_t OFF_CPB  = 19464192;   // (T,8)
constexpr size_t OFF_BIAS = 19595264;   // bf16 (8,256,4096) = 16.7 M ushort
// transposed weights live in regions that are dead at their time of use:
constexpr size_t OFF_WTC  = OFF_CTX;              // conv wt [1728][192]
constexpr size_t OFF_QT   = OFF_CTX + 331776;     // [192][192]
constexpr size_t OFF_KVT  = OFF_CTX + 368640;     // [192][384]
constexpr size_t OFF_SRT  = OFF_CTX + 442368;     // [192][192]
constexpr size_t OFF_PJT  = OFF_KMAP;             // [192][192], created AFTER attn

// ---------------- weight transposes ----------------
__global__ __launch_bounds__(256) void k_wt_conv(const float* __restrict__ pw,
                                                 float* __restrict__ wt) {
  int i = blockIdx.x * 256 + threadIdx.x;
  if (i >= 331776) return;
  int oc = i % 192, k = i / 192;
  wt[i] = pw[(size_t)oc * 1728 + k];
}
__global__ __launch_bounds__(256) void k_wt_gen(const float* __restrict__ src,
                                                float* __restrict__ dst, int O, int K) {
  int i = blockIdx.x * 256 + threadIdx.x;
  if (i >= O * K) return;
  int o = i % O, k = i / O;
  dst[i] = src[(size_t)o * K + k];
}

// ---------------- 3x3 conv; 2 output rows/lane, 12 oc/wave; grid (32,4,4) ----------------
__global__ __launch_bounds__(256) void k_conv(
    const float* __restrict__ x, const float* __restrict__ wtc,
    const float* __restrict__ bf, float* __restrict__ t) {
  __shared__ __align__(16) float wl[72 * 48];   // 13.8 KB [k][oc48]
  __shared__ float xl[8 * 4 * 66];              // 8.4 KB [ii][r(4 rows)][wp]
  const int tid = threadIdx.x;
  const int lane = tid & 63;
  const int wv = __builtin_amdgcn_readfirstlane(tid >> 6);
  const int h0 = blockIdx.x * 2;                // output rows h0, h0+1
  const int b = blockIdx.y;
  const int obase = blockIdx.z * 48;
  const int ow = obase + wv * 12;

  float acc0[12], acc1[12];
#pragma unroll
  for (int j = 0; j < 12; ++j) { acc0[j] = 0.f; acc1[j] = 0.f; }

  for (int ic0 = 0; ic0 < 24; ++ic0) {
    __syncthreads();
    // stage x: rows h0-1 .. h0+2 (4 rows) for 8 input channels
    for (int f = tid; f < 2112; f += 256) {
      int ii = f / 264;
      int rem = f - ii * 264;
      int r = rem / 66;
      int wp = rem - r * 66;
      int hh = h0 + r - 1, ww = wp - 1;
      float v = 0.f;
      if (hh >= 0 && hh < 64 && ww >= 0 && ww < 64)
        v = x[((size_t)(b * 192 + ic0 * 8 + ii) << 12) + (hh << 6) + ww];
      xl[(ii * 4 + r) * 66 + wp] = v;
    }
    // stage w: 72 k x 48 oc
    for (int f4 = tid; f4 < 864; f4 += 256) {
      int kk = f4 / 12, j = f4 - kk * 12;
      ((float4*)wl)[f4] =
          ((const float4*)(wtc + (size_t)(ic0 * 72 + kk) * 192 + obase))[j];
    }
    __syncthreads();
#pragma unroll 1
    for (int ii = 0; ii < 8; ++ii) {
#pragma unroll
      for (int r = 0; r < 3; ++r) {
        const float* xr0 = &xl[(ii * 4 + r) * 66 + lane];
        const float* xr1 = xr0 + 66;
        float a0 = xr0[0], a1 = xr0[1], a2 = xr0[2];
        float c0 = xr1[0], c1 = xr1[1], c2 = xr1[2];
#pragma unroll
        for (int kw = 0; kw < 3; ++kw) {
          float xv0 = (kw == 0) ? a0 : ((kw == 1) ? a1 : a2);
          float xv1 = (kw == 0) ? c0 : ((kw == 1) ? c1 : c2);
          const float4* wrow = (const float4*)&wl[(ii * 9 + r * 3 + kw) * 48 + wv * 12];
#pragma unroll
          for (int j4 = 0; j4 < 3; ++j4) {
            float4 w4 = wrow[j4];
            acc0[j4 * 4 + 0] += xv0 * w4.x;  acc1[j4 * 4 + 0] += xv1 * w4.x;
            acc0[j4 * 4 + 1] += xv0 * w4.y;  acc1[j4 * 4 + 1] += xv1 * w4.y;
            acc0[j4 * 4 + 2] += xv0 * w4.z;  acc1[j4 * 4 + 2] += xv1 * w4.z;
            acc0[j4 * 4 + 3] += xv0 * w4.w;  acc1[j4 * 4 + 3] += xv1 * w4.w;
          }
        }
      }
    }
  }
  float* out0 = t + ((size_t)b * 4096 + h0 * 64 + lane) * 192 + ow;
  float* out1 = out0 + 64 * 192;
#pragma unroll
  for (int j4 = 0; j4 < 3; ++j4) {
    float4 bb4 = *(const float4*)&bf[ow + j4 * 4];
    float4 v0, v1;
    v0.x = acc0[j4 * 4 + 0] + bb4.x;  v1.x = acc1[j4 * 4 + 0] + bb4.x;
    v0.y = acc0[j4 * 4 + 1] + bb4.y;  v1.y = acc1[j4 * 4 + 1] + bb4.y;
    v0.z = acc0[j4 * 4 + 2] + bb4.z;  v1.z = acc1[j4 * 4 + 2] + bb4.z;
    v0.w = acc0[j4 * 4 + 3] + bb4.w;  v1.w = acc1[j4 * 4 + 3] + bb4.w;
    ((float4*)out0)[j4] = v0;
    ((float4*)out1)[j4] = v1;
  }
}

// ---------------- LN over 192 channels, in-place (wave per row) ----------------
__global__ __launch_bounds__(256) void k_ln_rows(float* __restrict__ data,
    const float* __restrict__ g, const float* __restrict__ be, int rows) {
  int lane = threadIdx.x & 63;
  int wv = threadIdx.x >> 6;
  int row = blockIdx.x * 4 + wv;
  if (row >= rows) return;
  float* p = data + (size_t)row * 192;
  float v0 = p[lane], v1 = p[lane + 64], v2 = p[lane + 128];
  float s = v0 + v1 + v2;
  float sq = v0 * v0 + v1 * v1 + v2 * v2;
#pragma unroll
  for (int m = 32; m >= 1; m >>= 1) {
    s += __shfl_xor(s, m, 64);
    sq += __shfl_xor(sq, m, 64);
  }
  float mean = s * (1.f / 192.f);
  float var = sq * (1.f / 192.f) - mean * mean;
  float rstd = rsqrtf(var + 1e-5f);
  p[lane]       = (v0 - mean) * rstd * g[lane]       + be[lane];
  p[lane + 64]  = (v1 - mean) * rstd * g[lane + 64]  + be[lane + 64];
  p[lane + 128] = (v2 - mean) * rstd * g[lane + 128] + be[lane + 128];
}

// ======== GEMM tile core: xs[kk][px(66)], wl[kk][OCB], acc OCB/4 per lane ========
template <int OCB, typename StageX>
__device__ __forceinline__ void gemm_tiles(
    float* __restrict__ wl, float* __restrict__ xs, int tid, int lane, int wv,
    const float* __restrict__ wt, int ostr, int obase,
    float (&acc)[OCB / 4], StageX stage_x) {
  constexpr int NPF4 = OCB / 4;
  constexpr int NW4 = OCB / 16;
  for (int kt = 0; kt < 6; ++kt) {
    const int k0 = kt * 32;
    __syncthreads();
    stage_x(k0);
    for (int f4 = tid; f4 < 32 * NPF4; f4 += 256) {
      int kk = f4 / NPF4, j = f4 - kk * NPF4;
      ((float4*)wl)[f4] = ((const float4*)(wt + (size_t)(k0 + kk) * ostr + obase))[j];
    }
    __syncthreads();
#pragma unroll 4
    for (int kk = 0; kk < 32; ++kk) {
      float xv = xs[kk * 66 + lane];
      const float4* wrow = (const float4*)&wl[kk * OCB + wv * NPF4];
#pragma unroll
      for (int j4 = 0; j4 < NW4; ++j4) {
        float4 w4 = wrow[j4];
        acc[j4 * 4 + 0] += xv * w4.x;
        acc[j4 * 4 + 1] += xv * w4.y;
        acc[j4 * 4 + 2] += xv * w4.z;
        acc[j4 * 4 + 3] += xv * w4.w;
      }
    }
  }
}

// ---------------- q GEMM (96 oc = 4 heads/block) -> l2norm -> scaled ----------------
__global__ __launch_bounds__(256) void k_q(
    const float* __restrict__ t, const float* __restrict__ qt, const float* __restrict__ qb,
    const float* __restrict__ qe, const float* __restrict__ tmp, const float* __restrict__ ss,
    float* __restrict__ qno, float* __restrict__ qso) {
  __shared__ __align__(16) float wl[32 * 96];
  __shared__ float xs[32 * 66];
  const int tid = threadIdx.x;
  const int lane = tid & 63;
  const int wv = __builtin_amdgcn_readfirstlane(tid >> 6);
  const int n0 = blockIdx.x * 64;
  const int b = blockIdx.y;
  const int obase = blockIdx.z * 96;
  const int hh = blockIdx.z * 4 + wv;
  const int oc0 = obase + wv * 24;
  float acc[24];
#pragma unroll
  for (int j = 0; j < 24; ++j) acc[j] = 0.f;

  gemm_tiles<96>(wl, xs, tid, lane, wv, qt, 192, obase, acc,
    [&](int k0) {
      for (int f = tid; f < 2048; f += 256) {
        int nl = f >> 5, kk = f & 31;
        xs[kk * 66 + nl] = t[((size_t)b * 4096 + n0 + nl) * 192 + k0 + kk];
      }
    });

  const int n = n0 + lane;
  float ssv = ss[n];
  float sumsq = 0.f;
#pragma unroll
  for (int d = 0; d < 24; ++d) {
    float v = acc[d] + qb[oc0 + d];
    sumsq += v * v;
  }
  float rn = 1.f / fmaxf(sqrtf(sumsq), 1e-12f);
  float sp = log1pf(__expf(tmp[hh]));
#pragma unroll
  for (int d = 0; d < 24; ++d) {
    float qv = (acc[d] + qb[oc0 + d]) * rn;
    size_t o = ((size_t)(b * 8 + hh) * 24 + d) * 4096 + n;
    qno[o] = qv;
    qso[o] = (qv + qe[hh * 24 + d]) * sp * ssv;
  }
}

// ---------------- kv GEMM (96 of 384 oc/block) -> kmap[b][c][n] ----------------
__global__ __launch_bounds__(256) void k_kv(
    const float* __restrict__ t, const float* __restrict__ kvt, const float* __restrict__ kb_,
    float* __restrict__ kmap) {
  __shared__ __align__(16) float wl[32 * 96];
  __shared__ float xs[32 * 66];
  const int tid = threadIdx.x;
  const int lane = tid & 63;
  const int wv = __builtin_amdgcn_readfirstlane(tid >> 6);
  const int n0 = blockIdx.x * 64;
  const int b = blockIdx.y;
  const int obase = blockIdx.z * 96;
  const int oc0 = obase + wv * 24;
  const int n = n0 + lane;
  float acc[24];
#pragma unroll
  for (int j = 0; j < 24; ++j) acc[j] = 0.f;

  gemm_tiles<96>(wl, xs, tid, lane, wv, kvt, 384, obase, acc,
    [&](int k0) {
      for (int f = tid; f < 2048; f += 256) {
        int nl = f >> 5, kk = f & 31;
        xs[kk * 66 + nl] = t[((size_t)b * 4096 + n0 + nl) * 192 + k0 + kk];
      }
    });

  if (oc0 < 192) {
    float sumsq = 0.f;
#pragma unroll
    for (int d = 0; d < 24; ++d) {
      float v = acc[d] + kb_[oc0 + d];
      sumsq += v * v;
    }
    float rn = 1.f / fmaxf(sqrtf(sumsq), 1e-12f);
#pragma unroll
    for (int d = 0; d < 24; ++d)
      kmap[((size_t)b * 384 + oc0 + d) * 4096 + n] = (acc[d] + kb_[oc0 + d]) * rn;
  } else {
#pragma unroll
    for (int d = 0; d < 24; ++d)
      kmap[((size_t)b * 384 + oc0 + d) * 4096 + n] = acc[d] + kb_[oc0 + d];
  }
}

// ---------------- sr GEMM (48 oc/block) + exact gelu + 4x4 mean-pool ----------------
__device__ __forceinline__ float gelu_exact(float v) {
  float u = v * 0.70710678118654752f;
  float a = fabsf(u);
  float tt = 1.f / (1.f + 0.3275911f * a);
  float poly = ((((1.061405429f * tt - 1.453152027f) * tt + 1.421413741f) * tt
                 - 0.284496736f) * tt + 0.254829592f) * tt;
  float erfa = 1.f - poly * __expf(-a * a);
  float erfv = (u < 0.f) ? -erfa : erfa;
  return 0.5f * v * (1.f + erfv);
}

__global__ __launch_bounds__(256) void k_srpool(
    const float* __restrict__ t, const float* __restrict__ srt, const float* __restrict__ sb,
    float* __restrict__ pooled) {
  __shared__ __align__(16) float wl[32 * 48];
  __shared__ float xs[32 * 66];
  const int tid = threadIdx.x;
  const int lane = tid & 63;
  const int wv = __builtin_amdgcn_readfirstlane(tid >> 6);
  const int wx = blockIdx.x & 3;
  const int obase = (blockIdx.x >> 2) * 48;
  const int ph = blockIdx.y;
  const int b = blockIdx.z;
  const int oc0 = obase + wv * 12;
  float acc[12];
#pragma unroll
  for (int j = 0; j < 12; ++j) acc[j] = 0.f;

  gemm_tiles<48>(wl, xs, tid, lane, wv, srt, 192, obase, acc,
    [&](int k0) {
      for (int f = tid; f < 2048; f += 256) {
        int pl = f >> 5, kk = f & 31;
        int row = (ph * 4 + (pl >> 4)) * 64 + wx * 16 + (pl & 15);
        xs[kk * 66 + pl] = t[((size_t)b * 4096 + row) * 192 + k0 + kk];
      }
    });

#pragma unroll
  for (int j = 0; j < 12; ++j) {
    float gv = gelu_exact(acc[j] + sb[oc0 + j]);
    gv += __shfl_xor(gv, 1, 64);
    gv += __shfl_xor(gv, 2, 64);
    gv += __shfl_xor(gv, 16, 64);
    gv += __shfl_xor(gv, 32, 64);
    if ((lane & 51) == 0) {
      int cell = (lane >> 2) & 3;
      int p = ph * 16 + wx * 4 + cell;
      pooled[((size_t)b * 256 + p) * 192 + oc0 + j] = gv * (1.f / 16.f);
    }
  }
}

// ---------------- pooled kv (96 of 384 oc/block) -> kp/vp [b][h][m][24] ----------------
__global__ __launch_bounds__(256) void k_kvp(
    const float* __restrict__ pooled, const float* __restrict__ kvt, const float* __restrict__ kb_,
    float* __restrict__ kp, float* __restrict__ vp) {
  __shared__ __align__(16) float wl[32 * 96];
  __shared__ float xs[32 * 66];
  const int tid = threadIdx.x;
  const int lane = tid & 63;
  const int wv = __builtin_amdgcn_readfirstlane(tid >> 6);
  const int r0 = blockIdx.x * 64;
  const int obase = blockIdx.y * 96;
  const int oc0 = obase + wv * 24;
  const int row = r0 + lane;
  const int b = row >> 8;
  const int m = row & 255;
  float acc[24];
#pragma unroll
  for (int j = 0; j < 24; ++j) acc[j] = 0.f;

  gemm_tiles<96>(wl, xs, tid, lane, wv, kvt, 384, obase, acc,
    [&](int k0) {
      for (int f = tid; f < 2048; f += 256) {
        int nl = f >> 5, kk = f & 31;
        xs[kk * 66 + nl] = pooled[(size_t)(r0 + nl) * 192 + k0 + kk];
      }
    });

  if (oc0 < 192) {
    int hh = oc0 / 24;
    float sumsq = 0.f;
#pragma unroll
    for (int d = 0; d < 24; ++d) {
      float v = acc[d] + kb_[oc0 + d];
      sumsq += v * v;
    }
    float rn = 1.f / fmaxf(sqrtf(sumsq), 1e-12f);
#pragma unroll
    for (int d = 0; d < 24; ++d)
      kp[(((size_t)(b * 8 + hh)) * 256 + m) * 24 + d] = (acc[d] + kb_[oc0 + d]) * rn;
  } else {
    int hh = (oc0 - 192) / 24;
#pragma unroll
    for (int d = 0; d < 24; ++d)
      vp[(((size_t)(b * 8 + hh)) * 256 + m) * 24 + d] = acc[d] + kb_[oc0 + d];
  }
}

// ---------------- cpb MLP: (T,2) -> (T,8) ----------------
__global__ __launch_bounds__(256) void k_cpb(
    const float* __restrict__ coords, const float* __restrict__ c1w,
    const float* __restrict__ c1b, const float* __restrict__ c2w,
    const float* __restrict__ c2b, float* __restrict__ cpb, int T) {
  int i = blockIdx.x * 256 + threadIdx.x;
  if (i >= T) return;
  float x0 = coords[2 * i], y0 = coords[2 * i + 1];
  float a[8];
#pragma unroll
  for (int h = 0; h < 8; ++h) a[h] = c2b[h];
  for (int j = 0; j < 512; ++j) {
    float hv = fmaxf(c1w[2 * j] * x0 + c1w[2 * j + 1] * y0 + c1b[j], 0.f);
#pragma unroll
    for (int h = 0; h < 8; ++h) a[h] += hv * c2w[h * 512 + j];
  }
#pragma unroll
  for (int h = 0; h < 8; ++h) cpb[(size_t)i * 8 + h] = a[h];
}

// ---------------- pool bias gather: bt[h][m][n] (bf16) ----------------
__global__ __launch_bounds__(256) void k_bias(
    const int* __restrict__ rel, const float* __restrict__ cpb,
    unsigned short* __restrict__ bt) {
  int n = blockIdx.x * 256 + threadIdx.x;
  int m = blockIdx.y;
  int idx = rel[(size_t)n * 256 + m];
  const float4* c4 = (const float4*)(cpb + (size_t)idx * 8);
  float4 A = c4[0], Bv = c4[1];
  float vals[8] = {A.x, A.y, A.z, A.w, Bv.x, Bv.y, Bv.z, Bv.w};
#pragma unroll
  for (int h = 0; h < 8; ++h)
    bt[((size_t)(h * 256 + m)) * 4096 + n] = f2b(vals[h]);
}

// ---------------- fused attention (bias read bf16) ----------------
__global__ __launch_bounds__(256) void k_attn(
    const float* __restrict__ qs_g, const float* __restrict__ qn_g,
    const float* __restrict__ kmap, const float* __restrict__ kp, const float* __restrict__ vp,
    const unsigned short* __restrict__ bt, const float* __restrict__ rpb,
    const float* __restrict__ lt, const float* __restrict__ lb,
    float* __restrict__ ctx) {
  const int tid = threadIdx.x;
  const int lane = tid & 63;
  const int wv = __builtin_amdgcn_readfirstlane(tid >> 6);
  const int h = blockIdx.y;
  const int b = blockIdx.z;
  const int n = blockIdx.x * 256 + wv * 64 + lane;
  const int hpix = __builtin_amdgcn_readfirstlane(n >> 6);
  const int wpix = n & 63;
  const float SHIFT = 15.f;

  float qsv[24], qnv[24];
  const float* qsb = qs_g + ((size_t)(b * 8 + h) * 24) * 4096 + n;
  const float* qnb = qn_g + ((size_t)(b * 8 + h) * 24) * 4096 + n;
#pragma unroll
  for (int d = 0; d < 24; ++d) {
    qsv[d] = qsb[(size_t)d * 4096];
    qnv[d] = qnb[(size_t)d * 4096];
  }

  const float* ltp = lt + h * 216;
  const float* lbp = lb + h * 9;
  const float* rpp = rpb + h * 9;
  float wlv[9];
#pragma unroll
  for (int l = 0; l < 9; ++l) {
    float a0 = 0, a1 = 0, a2 = 0;
#pragma unroll
    for (int d = 0; d < 24; d += 3) {
      a0 += qnv[d] * ltp[d * 9 + l];
      a1 += qnv[d + 1] * ltp[(d + 1) * 9 + l];
      a2 += qnv[d + 2] * ltp[(d + 2) * 9 + l];
    }
    wlv[l] = a0 + a1 + a2 + lbp[l];
  }

  float ctxA[24], ctxB[24], ctxP[24];
#pragma unroll
  for (int d = 0; d < 24; ++d) { ctxA[d] = 0.f; ctxB[d] = 0.f; ctxP[d] = 0.f; }
  float S = 0.f;

  const float* kbase = kmap + ((size_t)b * 384 + h * 24) * 4096;
#pragma unroll
  for (int l = 0; l < 9; ++l) {
    const int dh = l / 3 - 1, dw = l % 3 - 1;
    const int hp = hpix + dh;
    if (hp < 0 || hp >= 64) continue;
    const int wp2 = wpix + dw;
    const bool okw = (wp2 >= 0) && (wp2 < 64);
    const int nn = (hp << 6) + wp2;
    const float* kb = kbase + nn;
    const float* vb = kb + (size_t)192 * 4096;
    float d0 = 0, d1 = 0, d2 = 0, d3 = 0;
#pragma unroll
    for (int d = 0; d < 24; d += 4) {
      d0 += qsv[d] * kb[(size_t)d * 4096];
      d1 += qsv[d + 1] * kb[(size_t)(d + 1) * 4096];
      d2 += qsv[d + 2] * kb[(size_t)(d + 2) * 4096];
      d3 += qsv[d + 3] * kb[(size_t)(d + 3) * 4096];
    }
    float p = okw ? __expf((d0 + d1) + (d2 + d3) + rpp[l] - SHIFT) : 0.f;
    S += p;
    float wll = wlv[l];
#pragma unroll
    for (int d = 0; d < 24; ++d) {
      float vv = okw ? vb[(size_t)d * 4096] : 0.f;
      ctxA[d] += wll * vv;
      ctxB[d] += p * vv;
    }
  }

  const float* kpb = kp + (size_t)(b * 8 + h) * 256 * 24;
  const float* vpb = vp + (size_t)(b * 8 + h) * 256 * 24;
  const unsigned short* bb = bt + (size_t)(h * 256) * 4096 + n;
#pragma unroll 2
  for (int m = 0; m < 256; ++m) {
    const float* kr = kpb + m * 24;
    const float* vr = vpb + m * 24;
    float d0 = 0, d1 = 0, d2 = 0, d3 = 0;
#pragma unroll
    for (int d = 0; d < 24; d += 4) {
      d0 += qsv[d] * kr[d];
      d1 += qsv[d + 1] * kr[d + 1];
      d2 += qsv[d + 2] * kr[d + 2];
      d3 += qsv[d + 3] * kr[d + 3];
    }
    float p = __expf((d0 + d1) + (d2 + d3) + b2f(bb[(size_t)m * 4096]) - SHIFT);
    S += p;
#pragma unroll
    for (int d = 0; d < 24; ++d) ctxP[d] += p * vr[d];
  }

  const float inv = 1.f / S;
  float* cb = ctx + ((size_t)(b * 8 + h) * 24) * 4096 + n;
#pragma unroll
  for (int d = 0; d < 24; ++d)
    cb[(size_t)d * 4096] = ctxA[d] + (ctxB[d] + ctxP[d]) * inv;
}

// ---------------- proj GEMM (96 oc/block) -> pout[b][o][n] + bias ----------------
__global__ __launch_bounds__(256) void k_projg(
    const float* __restrict__ ctx, const float* __restrict__ pjt, const float* __restrict__ pb,
    float* __restrict__ pout) {
  __shared__ __align__(16) float wl[32 * 96];
  __shared__ float xs[32 * 66];
  const int tid = threadIdx.x;
  const int lane = tid & 63;
  const int wv = __builtin_amdgcn_readfirstlane(tid >> 6);
  const int n0 = blockIdx.x * 64;
  const int b = blockIdx.y;
  const int obase = blockIdx.z * 96;
  const int oc0 = obase + wv * 24;
  const int n = n0 + lane;
  float acc[24];
#pragma unroll
  for (int j = 0; j < 24; ++j) acc[j] = 0.f;

  gemm_tiles<96>(wl, xs, tid, lane, wv, pjt, 192, obase, acc,
    [&](int k0) {
      for (int f = tid; f < 2048; f += 256) {
        int kk = f >> 6, nl = f & 63;
        xs[kk * 66 + nl] = ctx[((size_t)b * 192 + k0 + kk) * 4096 + n0 + nl];
      }
    });

#pragma unroll
  for (int d = 0; d < 24; ++d)
    pout[((size_t)b * 192 + oc0 + d) * 4096 + n] = acc[d] + pb[oc0 + d];
}

// ---------------- output LN over o (values in regs), out[b][o][n] ----------------
__global__ __launch_bounds__(256) void k_oln(
    const float* __restrict__ pout, const float* __restrict__ g,
    const float* __restrict__ be, float* __restrict__ out) {
  __shared__ float red[2][4][64];
  const int tid = threadIdx.x;
  const int lane = tid & 63;
  const int wv = __builtin_amdgcn_readfirstlane(tid >> 6);
  const int n0 = blockIdx.x * 64;
  const int b = blockIdx.y;
  const int o0 = wv * 48;
  float v[48];
  float s = 0.f, sq = 0.f;
#pragma unroll
  for (int j = 0; j < 48; ++j) {
    v[j] = pout[((size_t)b * 192 + o0 + j) * 4096 + n0 + lane];
    s += v[j];
    sq += v[j] * v[j];
  }
  red[0][wv][lane] = s;
  red[1][wv][lane] = sq;
  __syncthreads();
  float st = red[0][0][lane] + red[0][1][lane] + red[0][2][lane] + red[0][3][lane];
  float sqt = red[1][0][lane] + red[1][1][lane] + red[1][2][lane] + red[1][3][lane];
  float mean = st * (1.f / 192.f);
  float var = sqt * (1.f / 192.f) - mean * mean;
  float rstd = rsqrtf(var + 1e-5f);
#pragma unroll
  for (int j = 0; j < 48; ++j) {
    int o = o0 + j;
    out[((size_t)b * 192 + o) * 4096 + n0 + lane] = (v[j] - mean) * rstd * g[o] + be[o];
  }
}

// ---------------- host launcher ----------------
extern "C" void kernel_launch(void* const* d_in, const int* in_sizes, int n_in,
                              void* d_out, int out_size, void* d_ws, size_t ws_size,
                              hipStream_t stream) {
  float* w = (float*)d_ws;

  const float* x      = (const float*)d_in[0];
  const float* pe_w   = (const float*)d_in[1];
  const float* pe_b   = (const float*)d_in[2];
  const float* peln_g = (const float*)d_in[3];
  const float* peln_b = (const float*)d_in[4];
  const float* q_w    = (const float*)d_in[5];
  const float* q_b    = (const float*)d_in[6];
  const float* kv_w   = (const float*)d_in[7];
  const float* kv_b   = (const float*)d_in[8];
  const float* sr_w   = (const float*)d_in[9];
  const float* sr_b   = (const float*)d_in[10];
  const float* norm_g = (const float*)d_in[11];
  const float* norm_b = (const float*)d_in[12];
  const float* cpb1w  = (const float*)d_in[13];
  const float* cpb1b  = (const float*)d_in[14];
  const float* cpb2w  = (const float*)d_in[15];
  const float* cpb2b  = (const float*)d_in[16];
  const float* rpb    = (const float*)d_in[17];
  const float* lt     = (const float*)d_in[18];
  const float* lb     = (const float*)d_in[19];
  const float* qe     = (const float*)d_in[20];
  const float* temp   = (const float*)d_in[21];
  const float* proj_w = (const float*)d_in[22];
  const float* proj_b = (const float*)d_in[23];
  const float* oln_g  = (const float*)d_in[24];
  const float* oln_b  = (const float*)d_in[25];
  const int*   rel    = (const int*)d_in[26];
  const float* coords = (const float*)d_in[27];
  const float* ss     = (const float*)d_in[28];

  dim3 blk(256);
  k_wt_conv<<<dim3(1296), blk, 0, stream>>>(pe_w, w + OFF_WTC);
  k_wt_gen<<<dim3(144), blk, 0, stream>>>(q_w, w + OFF_QT, 192, 192);
  k_wt_gen<<<dim3(288), blk, 0, stream>>>(kv_w, w + OFF_KVT, 384, 192);
  k_wt_gen<<<dim3(144), blk, 0, stream>>>(sr_w, w + OFF_SRT, 192, 192);

  k_conv<<<dim3(32, 4, 4), blk, 0, stream>>>(x, w + OFF_WTC, pe_b, w + OFF_T);
  k_ln_rows<<<dim3(4096), blk, 0, stream>>>(w + OFF_T, peln_g, peln_b, 16384);
  k_q<<<dim3(64, 4, 2), blk, 0, stream>>>(w + OFF_T, w + OFF_QT, q_b, qe, temp, ss,
      w + OFF_QN, w + OFF_QS);
  k_kv<<<dim3(64, 4, 4), blk, 0, stream>>>(w + OFF_T, w + OFF_KVT, kv_b, w + OFF_KMAP);
  k_srpool<<<dim3(16, 16, 4), blk, 0, stream>>>(w + OFF_T, w + OFF_SRT, sr_b, w + OFF_POOL);
  k_ln_rows<<<dim3(256), blk, 0, stream>>>(w + OFF_POOL, norm_g, norm_b, 1024);
  k_kvp<<<dim3(16, 4), blk, 0, stream>>>(w + OFF_POOL, w + OFF_KVT, kv_b,
      w + OFF_KP, w + OFF_VP);
  int T = in_sizes[27] / 2;
  k_cpb<<<dim3((T + 255) / 256), blk, 0, stream>>>(coords, cpb1w, cpb1b, cpb2w, cpb2b,
      w + OFF_CPB, T);
  k_bias<<<dim3(16, 256), blk, 0, stream>>>(rel, w + OFF_CPB,
      (unsigned short*)(w + OFF_BIAS));
  k_attn<<<dim3(16, 8, 4), blk, 0, stream>>>(w + OFF_QS, w + OFF_QN, w + OFF_KMAP,
      w + OFF_KP, w + OFF_VP, (const unsigned short*)(w + OFF_BIAS), rpb, lt, lb,
      w + OFF_CTX);
  // proj path: QN region is dead after attn -> pout scratch; KMAP dead -> pjt
  k_wt_gen<<<dim3(144), blk, 0, stream>>>(proj_w, w + OFF_PJT, 192, 192);
  k_projg<<<dim3(64, 4, 2), blk, 0, stream>>>(w + OFF_CTX, w + OFF_PJT, proj_b,
      w + OFF_QN);
  k_oln<<<dim3(64, 4), blk, 0, stream>>>(w + OFF_QN, oln_g, oln_b, (float*)d_out);
}

// Round 9
// 753.440 us; speedup vs baseline: 4.0867x; 1.0074x over previous
//
#include <hip/hip_runtime.h>
#include <stdint.h>

// B=4, DIM=192, H=W=64, N=4096, HEADS=8, HD=24, SR=4, PLEN=256, LL=9
// All inputs f32, output f32.

__device__ __forceinline__ float b2f(unsigned short u) {
  return __uint_as_float(((unsigned)u) << 16);
}
__device__ __forceinline__ unsigned short f2b(float f) {
  unsigned x = __float_as_uint(f);
  return (unsigned short)((x + 0x7fffu + ((x >> 16) & 1u)) >> 16);
}

// ---------------- workspace layout (floats) ----------------
constexpr size_t OFF_T    = 0;          // (B,N,192)
constexpr size_t OFF_KMAP = 3145728;    // (B,384,N)
constexpr size_t OFF_QN   = 9437184;    // (B,8,24,N); reused as pout (B,192,N) after attn
constexpr size_t OFF_QS   = 12582912;   // (B,8,24,N)
constexpr size_t OFF_CTX  = 15728640;   // (B,8,24,N)  (early: scratch for W transposes)
constexpr size_t OFF_POOL = 18874368;   // (B,256,192)
constexpr size_t OFF_KP   = 19070976;   // (B,8,256,24)
constexpr size_t OFF_VP   = 19267584;   // (B,8,256,24)
constexpr size_t OFF_CPB  = 19464192;   // (T,8)
constexpr size_t OFF_BIAS = 19595264;   // bf16 (8,256,4096) = 16.7 M ushort
constexpr size_t OFF_WTC  = OFF_CTX;              // conv wt [1728][192]
constexpr size_t OFF_QT   = OFF_CTX + 331776;     // [192][192]
constexpr size_t OFF_KVT  = OFF_CTX + 368640;     // [192][384]
constexpr size_t OFF_SRT  = OFF_CTX + 442368;     // [192][192]
constexpr size_t OFF_PJT  = OFF_KMAP;             // [192][192], created AFTER attn

// ---------------- weight transposes ----------------
__global__ __launch_bounds__(256) void k_wt_conv(const float* __restrict__ pw,
                                                 float* __restrict__ wt) {
  int i = blockIdx.x * 256 + threadIdx.x;
  if (i >= 331776) return;
  int oc = i % 192, k = i / 192;
  wt[i] = pw[(size_t)oc * 1728 + k];
}
__global__ __launch_bounds__(256) void k_wt_gen(const float* __restrict__ src,
                                                float* __restrict__ dst, int O, int K) {
  int i = blockIdx.x * 256 + threadIdx.x;
  if (i >= O * K) return;
  int o = i % O, k = i / O;
  dst[i] = src[(size_t)o * K + k];
}

// ---------------- 3x3 conv; 2 rows/lane, 12 oc/wave, reg-prefetch pipeline ----------------
__global__ __launch_bounds__(256) void k_conv(
    const float* __restrict__ x, const float* __restrict__ wtc,
    const float* __restrict__ bf, float* __restrict__ t) {
  __shared__ __align__(16) float wl[72 * 48];   // 13.8 KB [k][oc48]
  __shared__ float xl[8 * 4 * 66];              // 8.4 KB [ii][r(4)][wp]
  const int tid = threadIdx.x;
  const int lane = tid & 63;
  const int wv = __builtin_amdgcn_readfirstlane(tid >> 6);
  const int h0 = blockIdx.x * 2;
  const int b = blockIdx.y;
  const int obase = blockIdx.z * 48;
  const int ow = obase + wv * 12;

  float acc0[12], acc1[12];
#pragma unroll
  for (int j = 0; j < 12; ++j) { acc0[j] = 0.f; acc1[j] = 0.f; }

  float xr[9];
  float4 wr[4];
  auto loadx = [&](int ic0) {
#pragma unroll
    for (int s = 0; s < 9; ++s) {
      int f = tid + s * 256;
      float v = 0.f;
      if (f < 2112) {
        int ii = f / 264;
        int rem = f - ii * 264;
        int r = rem / 66;
        int wp = rem - r * 66;
        int hh = h0 + r - 1, ww = wp - 1;
        if (hh >= 0 && hh < 64 && ww >= 0 && ww < 64)
          v = x[((size_t)(b * 192 + ic0 * 8 + ii) << 12) + (hh << 6) + ww];
      }
      xr[s] = v;
    }
  };
  auto loadw = [&](int ic0) {
#pragma unroll
    for (int s = 0; s < 4; ++s) {
      int f4 = tid + s * 256;
      if (f4 < 864) {
        int kk = f4 / 12, j = f4 - kk * 12;
        wr[s] = ((const float4*)(wtc + (size_t)(ic0 * 72 + kk) * 192 + obase))[j];
      }
    }
  };
  loadx(0); loadw(0);

  for (int ic0 = 0; ic0 < 24; ++ic0) {
    __syncthreads();
#pragma unroll
    for (int s = 0; s < 9; ++s) {
      int f = tid + s * 256;
      if (f < 2112) {
        int ii = f / 264;
        int rem = f - ii * 264;
        int r = rem / 66;
        int wp = rem - r * 66;
        xl[(ii * 4 + r) * 66 + wp] = xr[s];
      }
    }
#pragma unroll
    for (int s = 0; s < 4; ++s) {
      int f4 = tid + s * 256;
      if (f4 < 864) ((float4*)wl)[f4] = wr[s];
    }
    __syncthreads();
    if (ic0 < 23) { loadx(ic0 + 1); loadw(ic0 + 1); }
#pragma unroll 1
    for (int ii = 0; ii < 8; ++ii) {
#pragma unroll
      for (int r = 0; r < 3; ++r) {
        const float* xr0 = &xl[(ii * 4 + r) * 66 + lane];
        const float* xr1 = xr0 + 66;
        float a0 = xr0[0], a1 = xr0[1], a2 = xr0[2];
        float c0 = xr1[0], c1 = xr1[1], c2 = xr1[2];
#pragma unroll
        for (int kw = 0; kw < 3; ++kw) {
          float xv0 = (kw == 0) ? a0 : ((kw == 1) ? a1 : a2);
          float xv1 = (kw == 0) ? c0 : ((kw == 1) ? c1 : c2);
          const float4* wrow = (const float4*)&wl[(ii * 9 + r * 3 + kw) * 48 + wv * 12];
#pragma unroll
          for (int j4 = 0; j4 < 3; ++j4) {
            float4 w4 = wrow[j4];
            acc0[j4 * 4 + 0] += xv0 * w4.x;  acc1[j4 * 4 + 0] += xv1 * w4.x;
            acc0[j4 * 4 + 1] += xv0 * w4.y;  acc1[j4 * 4 + 1] += xv1 * w4.y;
            acc0[j4 * 4 + 2] += xv0 * w4.z;  acc1[j4 * 4 + 2] += xv1 * w4.z;
            acc0[j4 * 4 + 3] += xv0 * w4.w;  acc1[j4 * 4 + 3] += xv1 * w4.w;
          }
        }
      }
    }
  }
  float* out0 = t + ((size_t)b * 4096 + h0 * 64 + lane) * 192 + ow;
  float* out1 = out0 + 64 * 192;
#pragma unroll
  for (int j4 = 0; j4 < 3; ++j4) {
    float4 bb4 = *(const float4*)&bf[ow + j4 * 4];
    float4 v0, v1;
    v0.x = acc0[j4 * 4 + 0] + bb4.x;  v1.x = acc1[j4 * 4 + 0] + bb4.x;
    v0.y = acc0[j4 * 4 + 1] + bb4.y;  v1.y = acc1[j4 * 4 + 1] + bb4.y;
    v0.z = acc0[j4 * 4 + 2] + bb4.z;  v1.z = acc1[j4 * 4 + 2] + bb4.z;
    v0.w = acc0[j4 * 4 + 3] + bb4.w;  v1.w = acc1[j4 * 4 + 3] + bb4.w;
    ((float4*)out0)[j4] = v0;
    ((float4*)out1)[j4] = v1;
  }
}

// ---------------- LN over 192 channels, in-place (wave per row) ----------------
__global__ __launch_bounds__(256) void k_ln_rows(float* __restrict__ data,
    const float* __restrict__ g, const float* __restrict__ be, int rows) {
  int lane = threadIdx.x & 63;
  int wv = threadIdx.x >> 6;
  int row = blockIdx.x * 4 + wv;
  if (row >= rows) return;
  float* p = data + (size_t)row * 192;
  float v0 = p[lane], v1 = p[lane + 64], v2 = p[lane + 128];
  float s = v0 + v1 + v2;
  float sq = v0 * v0 + v1 * v1 + v2 * v2;
#pragma unroll
  for (int m = 32; m >= 1; m >>= 1) {
    s += __shfl_xor(s, m, 64);
    sq += __shfl_xor(sq, m, 64);
  }
  float mean = s * (1.f / 192.f);
  float var = sq * (1.f / 192.f) - mean * mean;
  float rstd = rsqrtf(var + 1e-5f);
  p[lane]       = (v0 - mean) * rstd * g[lane]       + be[lane];
  p[lane + 64]  = (v1 - mean) * rstd * g[lane + 64]  + be[lane + 64];
  p[lane + 128] = (v2 - mean) * rstd * g[lane + 128] + be[lane + 128];
}

// ======== GEMM tile core w/ register-prefetch dbuf ========
// xs[kk][px(66)], wl[kk][OCB]; gxv(k0,f)->value, gxd(f)->xs slot
template <int OCB, typename GXV, typename GXD>
__device__ __forceinline__ void gemm_tiles(
    float* __restrict__ wl, float* __restrict__ xs, int tid, int lane, int wv,
    const float* __restrict__ wt, int ostr, int obase,
    float (&acc)[OCB / 4], GXV gxv, GXD gxd) {
  constexpr int NPF4 = OCB / 4;
  constexpr int NW4 = OCB / 16;
  constexpr int NWR = (32 * NPF4 + 255) / 256;
  constexpr bool WEXACT = (32 * NPF4 % 256) == 0;
  float xr[8];
  float4 wr[NWR];
  auto loadx = [&](int k0) {
#pragma unroll
    for (int s = 0; s < 8; ++s) xr[s] = gxv(k0, tid + s * 256);
  };
  auto loadw = [&](int k0) {
#pragma unroll
    for (int s = 0; s < NWR; ++s) {
      int f4 = tid + s * 256;
      if (WEXACT || f4 < 32 * NPF4) {
        int kk = f4 / NPF4, j = f4 - kk * NPF4;
        wr[s] = ((const float4*)(wt + (size_t)(k0 + kk) * ostr + obase))[j];
      }
    }
  };
  loadx(0); loadw(0);
  for (int kt = 0; kt < 6; ++kt) {
    __syncthreads();
#pragma unroll
    for (int s = 0; s < 8; ++s) xs[gxd(tid + s * 256)] = xr[s];
#pragma unroll
    for (int s = 0; s < NWR; ++s) {
      int f4 = tid + s * 256;
      if (WEXACT || f4 < 32 * NPF4) ((float4*)wl)[f4] = wr[s];
    }
    __syncthreads();
    if (kt < 5) { loadx((kt + 1) * 32); loadw((kt + 1) * 32); }
#pragma unroll 4
    for (int kk = 0; kk < 32; ++kk) {
      float xv = xs[kk * 66 + lane];
      const float4* wrow = (const float4*)&wl[kk * OCB + wv * NW4 * 4];
#pragma unroll
      for (int j4 = 0; j4 < NW4; ++j4) {
        float4 w4 = wrow[j4];
        acc[j4 * 4 + 0] += xv * w4.x;
        acc[j4 * 4 + 1] += xv * w4.y;
        acc[j4 * 4 + 2] += xv * w4.z;
        acc[j4 * 4 + 3] += xv * w4.w;
      }
    }
  }
}

// ---------------- q GEMM (96 oc = 4 heads/block) -> l2norm -> scaled ----------------
__global__ __launch_bounds__(256) void k_q(
    const float* __restrict__ t, const float* __restrict__ qt, const float* __restrict__ qb,
    const float* __restrict__ qe, const float* __restrict__ tmp, const float* __restrict__ ss,
    float* __restrict__ qno, float* __restrict__ qso) {
  __shared__ __align__(16) float wl[32 * 96];
  __shared__ float xs[32 * 66];
  const int tid = threadIdx.x;
  const int lane = tid & 63;
  const int wv = __builtin_amdgcn_readfirstlane(tid >> 6);
  const int n0 = blockIdx.x * 64;
  const int b = blockIdx.y;
  const int obase = blockIdx.z * 96;
  const int hh = blockIdx.z * 4 + wv;
  const int oc0 = obase + wv * 24;
  float acc[24];
#pragma unroll
  for (int j = 0; j < 24; ++j) acc[j] = 0.f;

  gemm_tiles<96>(wl, xs, tid, lane, wv, qt, 192, obase, acc,
    [&](int k0, int f) {
      int nl = f >> 5, kk = f & 31;
      return t[((size_t)b * 4096 + n0 + nl) * 192 + k0 + kk];
    },
    [&](int f) { return (f & 31) * 66 + (f >> 5); });

  const int n = n0 + lane;
  float ssv = ss[n];
  float sumsq = 0.f;
#pragma unroll
  for (int d = 0; d < 24; ++d) {
    float v = acc[d] + qb[oc0 + d];
    sumsq += v * v;
  }
  float rn = 1.f / fmaxf(sqrtf(sumsq), 1e-12f);
  float sp = log1pf(__expf(tmp[hh]));
#pragma unroll
  for (int d = 0; d < 24; ++d) {
    float qv = (acc[d] + qb[oc0 + d]) * rn;
    size_t o = ((size_t)(b * 8 + hh) * 24 + d) * 4096 + n;
    qno[o] = qv;
    qso[o] = (qv + qe[hh * 24 + d]) * sp * ssv;
  }
}

// ---------------- kv GEMM (96 of 384 oc/block) -> kmap[b][c][n] ----------------
__global__ __launch_bounds__(256) void k_kv(
    const float* __restrict__ t, const float* __restrict__ kvt, const float* __restrict__ kb_,
    float* __restrict__ kmap) {
  __shared__ __align__(16) float wl[32 * 96];
  __shared__ float xs[32 * 66];
  const int tid = threadIdx.x;
  const int lane = tid & 63;
  const int wv = __builtin_amdgcn_readfirstlane(tid >> 6);
  const int n0 = blockIdx.x * 64;
  const int b = blockIdx.y;
  const int obase = blockIdx.z * 96;
  const int oc0 = obase + wv * 24;
  const int n = n0 + lane;
  float acc[24];
#pragma unroll
  for (int j = 0; j < 24; ++j) acc[j] = 0.f;

  gemm_tiles<96>(wl, xs, tid, lane, wv, kvt, 384, obase, acc,
    [&](int k0, int f) {
      int nl = f >> 5, kk = f & 31;
      return t[((size_t)b * 4096 + n0 + nl) * 192 + k0 + kk];
    },
    [&](int f) { return (f & 31) * 66 + (f >> 5); });

  if (oc0 < 192) {
    float sumsq = 0.f;
#pragma unroll
    for (int d = 0; d < 24; ++d) {
      float v = acc[d] + kb_[oc0 + d];
      sumsq += v * v;
    }
    float rn = 1.f / fmaxf(sqrtf(sumsq), 1e-12f);
#pragma unroll
    for (int d = 0; d < 24; ++d)
      kmap[((size_t)b * 384 + oc0 + d) * 4096 + n] = (acc[d] + kb_[oc0 + d]) * rn;
  } else {
#pragma unroll
    for (int d = 0; d < 24; ++d)
      kmap[((size_t)b * 384 + oc0 + d) * 4096 + n] = acc[d] + kb_[oc0 + d];
  }
}

// ---------------- sr GEMM (48 oc/block) + exact gelu + 4x4 mean-pool ----------------
__device__ __forceinline__ float gelu_exact(float v) {
  float u = v * 0.70710678118654752f;
  float a = fabsf(u);
  float tt = 1.f / (1.f + 0.3275911f * a);
  float poly = ((((1.061405429f * tt - 1.453152027f) * tt + 1.421413741f) * tt
                 - 0.284496736f) * tt + 0.254829592f) * tt;
  float erfa = 1.f - poly * __expf(-a * a);
  float erfv = (u < 0.f) ? -erfa : erfa;
  return 0.5f * v * (1.f + erfv);
}

__global__ __launch_bounds__(256) void k_srpool(
    const float* __restrict__ t, const float* __restrict__ srt, const float* __restrict__ sb,
    float* __restrict__ pooled) {
  __shared__ __align__(16) float wl[32 * 48];
  __shared__ float xs[32 * 66];
  const int tid = threadIdx.x;
  const int lane = tid & 63;
  const int wv = __builtin_amdgcn_readfirstlane(tid >> 6);
  const int wx = blockIdx.x & 3;
  const int obase = (blockIdx.x >> 2) * 48;
  const int ph = blockIdx.y;
  const int b = blockIdx.z;
  const int oc0 = obase + wv * 12;
  float acc[12];
#pragma unroll
  for (int j = 0; j < 12; ++j) acc[j] = 0.f;

  gemm_tiles<48>(wl, xs, tid, lane, wv, srt, 192, obase, acc,
    [&](int k0, int f) {
      int pl = f >> 5, kk = f & 31;
      int row = (ph * 4 + (pl >> 4)) * 64 + wx * 16 + (pl & 15);
      return t[((size_t)b * 4096 + row) * 192 + k0 + kk];
    },
    [&](int f) { return (f & 31) * 66 + (f >> 5); });

#pragma unroll
  for (int j = 0; j < 12; ++j) {
    float gv = gelu_exact(acc[j] + sb[oc0 + j]);
    gv += __shfl_xor(gv, 1, 64);
    gv += __shfl_xor(gv, 2, 64);
    gv += __shfl_xor(gv, 16, 64);
    gv += __shfl_xor(gv, 32, 64);
    if ((lane & 51) == 0) {
      int cell = (lane >> 2) & 3;
      int p = ph * 16 + wx * 4 + cell;
      pooled[((size_t)b * 256 + p) * 192 + oc0 + j] = gv * (1.f / 16.f);
    }
  }
}

// ---------------- pooled kv (96 of 384 oc/block) -> kp/vp [b][h][m][24] ----------------
__global__ __launch_bounds__(256) void k_kvp(
    const float* __restrict__ pooled, const float* __restrict__ kvt, const float* __restrict__ kb_,
    float* __restrict__ kp, float* __restrict__ vp) {
  __shared__ __align__(16) float wl[32 * 96];
  __shared__ float xs[32 * 66];
  const int tid = threadIdx.x;
  const int lane = tid & 63;
  const int wv = __builtin_amdgcn_readfirstlane(tid >> 6);
  const int r0 = blockIdx.x * 64;
  const int obase = blockIdx.y * 96;
  const int oc0 = obase + wv * 24;
  const int row = r0 + lane;
  const int b = row >> 8;
  const int m = row & 255;
  float acc[24];
#pragma unroll
  for (int j = 0; j < 24; ++j) acc[j] = 0.f;

  gemm_tiles<96>(wl, xs, tid, lane, wv, kvt, 384, obase, acc,
    [&](int k0, int f) {
      int nl = f >> 5, kk = f & 31;
      return pooled[(size_t)(r0 + nl) * 192 + k0 + kk];
    },
    [&](int f) { return (f & 31) * 66 + (f >> 5); });

  if (oc0 < 192) {
    int hh = oc0 / 24;
    float sumsq = 0.f;
#pragma unroll
    for (int d = 0; d < 24; ++d) {
      float v = acc[d] + kb_[oc0 + d];
      sumsq += v * v;
    }
    float rn = 1.f / fmaxf(sqrtf(sumsq), 1e-12f);
#pragma unroll
    for (int d = 0; d < 24; ++d)
      kp[(((size_t)(b * 8 + hh)) * 256 + m) * 24 + d] = (acc[d] + kb_[oc0 + d]) * rn;
  } else {
    int hh = (oc0 - 192) / 24;
#pragma unroll
    for (int d = 0; d < 24; ++d)
      vp[(((size_t)(b * 8 + hh)) * 256 + m) * 24 + d] = acc[d] + kb_[oc0 + d];
  }
}

// ---------------- cpb MLP: (T,2) -> (T,8), weights staged in LDS ----------------
__global__ __launch_bounds__(256) void k_cpb(
    const float* __restrict__ coords, const float* __restrict__ c1w,
    const float* __restrict__ c1b, const float* __restrict__ c2w,
    const float* __restrict__ c2b, float* __restrict__ cpb, int T) {
  __shared__ float s1w[1024];     // [j][2]
  __shared__ float s1b[512];
  __shared__ __align__(16) float s2w[512 * 8];  // [j][h]
  const int tid = threadIdx.x;
  for (int f = tid; f < 1024; f += 256) s1w[f] = c1w[f];
  for (int f = tid; f < 512; f += 256) s1b[f] = c1b[f];
  for (int f = tid; f < 4096; f += 256) {
    int h = f >> 9, j = f & 511;
    s2w[j * 8 + h] = c2w[f];
  }
  __syncthreads();
  int i = blockIdx.x * 256 + tid;
  int ic = (i < T) ? i : (T - 1);
  float x0 = coords[2 * ic], y0 = coords[2 * ic + 1];
  float a[8];
#pragma unroll
  for (int h = 0; h < 8; ++h) a[h] = c2b[h];
#pragma unroll 4
  for (int j = 0; j < 512; ++j) {
    float hv = fmaxf(s1w[2 * j] * x0 + s1w[2 * j + 1] * y0 + s1b[j], 0.f);
    const float4* w2 = (const float4*)&s2w[j * 8];
    float4 wA = w2[0], wB = w2[1];
    a[0] += hv * wA.x; a[1] += hv * wA.y; a[2] += hv * wA.z; a[3] += hv * wA.w;
    a[4] += hv * wB.x; a[5] += hv * wB.y; a[6] += hv * wB.z; a[7] += hv * wB.w;
  }
  if (i < T) {
#pragma unroll
    for (int h = 0; h < 8; ++h) cpb[(size_t)i * 8 + h] = a[h];
  }
}

// ---------------- pool bias gather: bt[h][m][n] (bf16) ----------------
__global__ __launch_bounds__(256) void k_bias(
    const int* __restrict__ rel, const float* __restrict__ cpb,
    unsigned short* __restrict__ bt) {
  int n = blockIdx.x * 256 + threadIdx.x;
  int m = blockIdx.y;
  int idx = rel[(size_t)n * 256 + m];
  const float4* c4 = (const float4*)(cpb + (size_t)idx * 8);
  float4 A = c4[0], Bv = c4[1];
  float vals[8] = {A.x, A.y, A.z, A.w, Bv.x, Bv.y, Bv.z, Bv.w};
#pragma unroll
  for (int h = 0; h < 8; ++h)
    bt[((size_t)(h * 256 + m)) * 4096 + n] = f2b(vals[h]);
}

// ---------------- fused attention; kp/vp staged in LDS ----------------
__global__ __launch_bounds__(256) void k_attn(
    const float* __restrict__ qs_g, const float* __restrict__ qn_g,
    const float* __restrict__ kmap, const float* __restrict__ kp, const float* __restrict__ vp,
    const unsigned short* __restrict__ bt, const float* __restrict__ rpb,
    const float* __restrict__ lt, const float* __restrict__ lb,
    float* __restrict__ ctx) {
  __shared__ __align__(16) float kl[256 * 24];  // 24 KB
  __shared__ __align__(16) float vl[256 * 24];  // 24 KB
  const int tid = threadIdx.x;
  const int lane = tid & 63;
  const int wv = __builtin_amdgcn_readfirstlane(tid >> 6);
  const int h = blockIdx.y;
  const int b = blockIdx.z;
  const int n = blockIdx.x * 256 + wv * 64 + lane;
  const int hpix = __builtin_amdgcn_readfirstlane(n >> 6);
  const int wpix = n & 63;
  const float SHIFT = 15.f;

  {
    const float4* kps = (const float4*)(kp + (size_t)(b * 8 + h) * 6144);
    const float4* vps = (const float4*)(vp + (size_t)(b * 8 + h) * 6144);
    float4* kld = (float4*)kl;
    float4* vld = (float4*)vl;
    for (int f = tid; f < 1536; f += 256) {
      kld[f] = kps[f];
      vld[f] = vps[f];
    }
  }

  float qsv[24], qnv[24];
  const float* qsb = qs_g + ((size_t)(b * 8 + h) * 24) * 4096 + n;
  const float* qnb = qn_g + ((size_t)(b * 8 + h) * 24) * 4096 + n;
#pragma unroll
  for (int d = 0; d < 24; ++d) {
    qsv[d] = qsb[(size_t)d * 4096];
    qnv[d] = qnb[(size_t)d * 4096];
  }

  const float* ltp = lt + h * 216;
  const float* lbp = lb + h * 9;
  const float* rpp = rpb + h * 9;
  float wlv[9];
#pragma unroll
  for (int l = 0; l < 9; ++l) {
    float a0 = 0, a1 = 0, a2 = 0;
#pragma unroll
    for (int d = 0; d < 24; d += 3) {
      a0 += qnv[d] * ltp[d * 9 + l];
      a1 += qnv[d + 1] * ltp[(d + 1) * 9 + l];
      a2 += qnv[d + 2] * ltp[(d + 2) * 9 + l];
    }
    wlv[l] = a0 + a1 + a2 + lbp[l];
  }

  float ctxA[24], ctxB[24], ctxP[24];
#pragma unroll
  for (int d = 0; d < 24; ++d) { ctxA[d] = 0.f; ctxB[d] = 0.f; ctxP[d] = 0.f; }
  float S = 0.f;

  const float* kbase = kmap + ((size_t)b * 384 + h * 24) * 4096;
#pragma unroll
  for (int l = 0; l < 9; ++l) {
    const int dh = l / 3 - 1, dw = l % 3 - 1;
    const int hp = hpix + dh;
    if (hp < 0 || hp >= 64) continue;
    const int wp2 = wpix + dw;
    const bool okw = (wp2 >= 0) && (wp2 < 64);
    const int nn = (hp << 6) + wp2;
    const float* kb = kbase + nn;
    const float* vb = kb + (size_t)192 * 4096;
    float d0 = 0, d1 = 0, d2 = 0, d3 = 0;
#pragma unroll
    for (int d = 0; d < 24; d += 4) {
      d0 += qsv[d] * kb[(size_t)d * 4096];
      d1 += qsv[d + 1] * kb[(size_t)(d + 1) * 4096];
      d2 += qsv[d + 2] * kb[(size_t)(d + 2) * 4096];
      d3 += qsv[d + 3] * kb[(size_t)(d + 3) * 4096];
    }
    float p = okw ? __expf((d0 + d1) + (d2 + d3) + rpp[l] - SHIFT) : 0.f;
    S += p;
    float wll = wlv[l];
#pragma unroll
    for (int d = 0; d < 24; ++d) {
      float vv = okw ? vb[(size_t)d * 4096] : 0.f;
      ctxA[d] += wll * vv;
      ctxB[d] += p * vv;
    }
  }

  __syncthreads();
  const unsigned short* bb = bt + (size_t)(h * 256) * 4096 + n;
#pragma unroll 2
  for (int m = 0; m < 256; ++m) {
    const float4* kr4 = (const float4*)&kl[m * 24];
    const float4* vr4 = (const float4*)&vl[m * 24];
    float d0 = 0, d1 = 0, d2 = 0, d3 = 0;
#pragma unroll
    for (int q4 = 0; q4 < 6; ++q4) {
      float4 k4 = kr4[q4];
      d0 += qsv[q4 * 4 + 0] * k4.x;
      d1 += qsv[q4 * 4 + 1] * k4.y;
      d2 += qsv[q4 * 4 + 2] * k4.z;
      d3 += qsv[q4 * 4 + 3] * k4.w;
    }
    float p = __expf((d0 + d1) + (d2 + d3) + b2f(bb[(size_t)m * 4096]) - SHIFT);
    S += p;
#pragma unroll
    for (int q4 = 0; q4 < 6; ++q4) {
      float4 v4 = vr4[q4];
      ctxP[q4 * 4 + 0] += p * v4.x;
      ctxP[q4 * 4 + 1] += p * v4.y;
      ctxP[q4 * 4 + 2] += p * v4.z;
      ctxP[q4 * 4 + 3] += p * v4.w;
    }
  }

  const float inv = 1.f / S;
  float* cb = ctx + ((size_t)(b * 8 + h) * 24) * 4096 + n;
#pragma unroll
  for (int d = 0; d < 24; ++d)
    cb[(size_t)d * 4096] = ctxA[d] + (ctxB[d] + ctxP[d]) * inv;
}

// ---------------- proj GEMM (96 oc/block) -> pout[b][o][n] + bias ----------------
__global__ __launch_bounds__(256) void k_projg(
    const float* __restrict__ ctx, const float* __restrict__ pjt, const float* __restrict__ pb,
    float* __restrict__ pout) {
  __shared__ __align__(16) float wl[32 * 96];
  __shared__ float xs[32 * 66];
  const int tid = threadIdx.x;
  const int lane = tid & 63;
  const int wv = __builtin_amdgcn_readfirstlane(tid >> 6);
  const int n0 = blockIdx.x * 64;
  const int b = blockIdx.y;
  const int obase = blockIdx.z * 96;
  const int oc0 = obase + wv * 24;
  const int n = n0 + lane;
  float acc[24];
#pragma unroll
  for (int j = 0; j < 24; ++j) acc[j] = 0.f;

  gemm_tiles<96>(wl, xs, tid, lane, wv, pjt, 192, obase, acc,
    [&](int k0, int f) {
      int kk = f >> 6, nl = f & 63;
      return ctx[((size_t)b * 192 + k0 + kk) * 4096 + n0 + nl];
    },
    [&](int f) { return (f >> 6) * 66 + (f & 63); });

#pragma unroll
  for (int d = 0; d < 24; ++d)
    pout[((size_t)b * 192 + oc0 + d) * 4096 + n] = acc[d] + pb[oc0 + d];
}

// ---------------- output LN over o (values in regs), out[b][o][n] ----------------
__global__ __launch_bounds__(256) void k_oln(
    const float* __restrict__ pout, const float* __restrict__ g,
    const float* __restrict__ be, float* __restrict__ out) {
  __shared__ float red[2][4][64];
  const int tid = threadIdx.x;
  const int lane = tid & 63;
  const int wv = __builtin_amdgcn_readfirstlane(tid >> 6);
  const int n0 = blockIdx.x * 64;
  const int b = blockIdx.y;
  const int o0 = wv * 48;
  float v[48];
  float s = 0.f, sq = 0.f;
#pragma unroll
  for (int j = 0; j < 48; ++j) {
    v[j] = pout[((size_t)b * 192 + o0 + j) * 4096 + n0 + lane];
    s += v[j];
    sq += v[j] * v[j];
  }
  red[0][wv][lane] = s;
  red[1][wv][lane] = sq;
  __syncthreads();
  float st = red[0][0][lane] + red[0][1][lane] + red[0][2][lane] + red[0][3][lane];
  float sqt = red[1][0][lane] + red[1][1][lane] + red[1][2][lane] + red[1][3][lane];
  float mean = st * (1.f / 192.f);
  float var = sqt * (1.f / 192.f) - mean * mean;
  float rstd = rsqrtf(var + 1e-5f);
#pragma unroll
  for (int j = 0; j < 48; ++j) {
    int o = o0 + j;
    out[((size_t)b * 192 + o) * 4096 + n0 + lane] = (v[j] - mean) * rstd * g[o] + be[o];
  }
}

// ---------------- host launcher ----------------
extern "C" void kernel_launch(void* const* d_in, const int* in_sizes, int n_in,
                              void* d_out, int out_size, void* d_ws, size_t ws_size,
                              hipStream_t stream) {
  float* w = (float*)d_ws;

  const float* x      = (const float*)d_in[0];
  const float* pe_w   = (const float*)d_in[1];
  const float* pe_b   = (const float*)d_in[2];
  const float* peln_g = (const float*)d_in[3];
  const float* peln_b = (const float*)d_in[4];
  const float* q_w    = (const float*)d_in[5];
  const float* q_b    = (const float*)d_in[6];
  const float* kv_w   = (const float*)d_in[7];
  const float* kv_b   = (const float*)d_in[8];
  const float* sr_w   = (const float*)d_in[9];
  const float* sr_b   = (const float*)d_in[10];
  const float* norm_g = (const float*)d_in[11];
  const float* norm_b = (const float*)d_in[12];
  const float* cpb1w  = (const float*)d_in[13];
  const float* cpb1b  = (const float*)d_in[14];
  const float* cpb2w  = (const float*)d_in[15];
  const float* cpb2b  = (const float*)d_in[16];
  const float* rpb    = (const float*)d_in[17];
  const float* lt     = (const float*)d_in[18];
  const float* lb     = (const float*)d_in[19];
  const float* qe     = (const float*)d_in[20];
  const float* temp   = (const float*)d_in[21];
  const float* proj_w = (const float*)d_in[22];
  const float* proj_b = (const float*)d_in[23];
  const float* oln_g  = (const float*)d_in[24];
  const float* oln_b  = (const float*)d_in[25];
  const int*   rel    = (const int*)d_in[26];
  const float* coords = (const float*)d_in[27];
  const float* ss     = (const float*)d_in[28];

  dim3 blk(256);
  k_wt_conv<<<dim3(1296), blk, 0, stream>>>(pe_w, w + OFF_WTC);
  k_wt_gen<<<dim3(144), blk, 0, stream>>>(q_w, w + OFF_QT, 192, 192);
  k_wt_gen<<<dim3(288), blk, 0, stream>>>(kv_w, w + OFF_KVT, 384, 192);
  k_wt_gen<<<dim3(144), blk, 0, stream>>>(sr_w, w + OFF_SRT, 192, 192);

  k_conv<<<dim3(32, 4, 4), blk, 0, stream>>>(x, w + OFF_WTC, pe_b, w + OFF_T);
  k_ln_rows<<<dim3(4096), blk, 0, stream>>>(w + OFF_T, peln_g, peln_b, 16384);
  k_q<<<dim3(64, 4, 2), blk, 0, stream>>>(w + OFF_T, w + OFF_QT, q_b, qe, temp, ss,
      w + OFF_QN, w + OFF_QS);
  k_kv<<<dim3(64, 4, 4), blk, 0, stream>>>(w + OFF_T, w + OFF_KVT, kv_b, w + OFF_KMAP);
  k_srpool<<<dim3(16, 16, 4), blk, 0, stream>>>(w + OFF_T, w + OFF_SRT, sr_b, w + OFF_POOL);
  k_ln_rows<<<dim3(256), blk, 0, stream>>>(w + OFF_POOL, norm_g, norm_b, 1024);
  k_kvp<<<dim3(16, 4), blk, 0, stream>>>(w + OFF_POOL, w + OFF_KVT, kv_b,
      w + OFF_KP, w + OFF_VP);
  int T = in_sizes[27] / 2;
  k_cpb<<<dim3((T + 255) / 256), blk, 0, stream>>>(coords, cpb1w, cpb1b, cpb2w, cpb2b,
      w + OFF_CPB, T);
  k_bias<<<dim3(16, 256), blk, 0, stream>>>(rel, w + OFF_CPB,
      (unsigned short*)(w + OFF_BIAS));
  k_attn<<<dim3(16, 8, 4), blk, 0, stream>>>(w + OFF_QS, w + OFF_QN, w + OFF_KMAP,
      w + OFF_KP, w + OFF_VP, (const unsigned short*)(w + OFF_BIAS), rpb, lt, lb,
      w + OFF_CTX);
  k_wt_gen<<<dim3(144), blk, 0, stream>>>(proj_w, w + OFF_PJT, 192, 192);
  k_projg<<<dim3(64, 4, 2), blk, 0, stream>>>(w + OFF_CTX, w + OFF_PJT, proj_b,
      w + OFF_QN);
  k_oln<<<dim3(64, 4), blk, 0, stream>>>(w + OFF_QN, oln_g, oln_b, (float*)d_out);
}